// Round 1
// baseline (917.458 us; speedup 1.0000x reference)
//
#include <hip/hip_runtime.h>
#include <cstdint>
#include <cstddef>

#define D 128
#define KC 32
#define NTILE 64

// ---------------- CSR build ----------------

__global__ __launch_bounds__(256) void count_kernel(const int* __restrict__ dst,
                                                    int* __restrict__ cnt, int E) {
    int e = blockIdx.x * 256 + threadIdx.x;
    if (e < E) atomicAdd(&cnt[dst[e]], 1);
}

__global__ __launch_bounds__(1024) void scan_kernel(const int* __restrict__ cnt,
                                                    int* __restrict__ row_ptr, int N) {
    __shared__ int s[1024];
    int t = threadIdx.x;
    int chunk = (N + 1023) >> 10;
    int beg = t * chunk;
    int end = min(beg + chunk, N);
    int sum = 0;
    for (int i = beg; i < end; ++i) sum += cnt[i];
    s[t] = sum;
    __syncthreads();
    for (int off = 1; off < 1024; off <<= 1) {
        int v = (t >= off) ? s[t - off] : 0;
        __syncthreads();
        s[t] += v;
        __syncthreads();
    }
    int run = s[t] - sum;  // exclusive prefix of this thread's chunk
    for (int i = beg; i < end; ++i) { row_ptr[i] = run; run += cnt[i]; }
    if (t == 1023) row_ptr[N] = s[1023];
}

__global__ __launch_bounds__(256) void fill_kernel(const int* __restrict__ src,
                                                   const int* __restrict__ dst,
                                                   const int* __restrict__ row_ptr,
                                                   int* __restrict__ cur,
                                                   int* __restrict__ csr, int E) {
    int e = blockIdx.x * 256 + threadIdx.x;
    if (e < E) {
        int d = dst[e];
        int p = atomicAdd(&cur[d], 1);
        csr[row_ptr[d] + p] = src[e];
    }
}

// ---------------- mean aggregation: one wave per node ----------------

__global__ __launch_bounds__(256) void agg_kernel(const float* __restrict__ xin,
                                                  const int* __restrict__ csr,
                                                  const int* __restrict__ row_ptr,
                                                  float* __restrict__ agg, int N) {
    int node = blockIdx.x * 4 + (threadIdx.x >> 6);
    if (node >= N) return;
    int lane = threadIdx.x & 63;
    int beg = row_ptr[node], end = row_ptr[node + 1];
    float ax = 0.f, ay = 0.f;
    for (int e = beg; e < end; ++e) {
        int s = csr[e];
        float2 v = ((const float2*)(xin + (size_t)s * D))[lane];
        ax += v.x;
        ay += v.y;
    }
    float inv = 1.0f / fmaxf((float)(end - beg), 1.0f);
    float2 o;
    o.x = ax * inv;
    o.y = ay * inv;
    ((float2*)(agg + (size_t)node * D))[lane] = o;
}

// ---------------- fused GEMM: out = agg @ Wl^T + xin @ Wr^T + b (+relu) ----------------
// Treated as [N,256] @ [128,256]^T with K = concat(agg-k, x-k).
// Block: 256 threads, 64 nodes x 128 outputs. Per-thread tile 8n x 4j.

__global__ __launch_bounds__(256) void gemm_kernel(const float* __restrict__ Aagg,
                                                   const float* __restrict__ Ax,
                                                   const float* __restrict__ Wl,
                                                   const float* __restrict__ Wr,
                                                   const float* __restrict__ bias,
                                                   float* __restrict__ out,
                                                   int N, int relu) {
    __shared__ float sW[KC][D];      // 16 KB, k-major
    __shared__ float sA[KC][NTILE];  // 8 KB, k-major
    int tid = threadIdx.x;
    int n0 = blockIdx.x * NTILE;
    int jg = tid & 31;   // j = jg*4 .. +3
    int ng = tid >> 5;   // nodes n0 + ng*8 .. +7

    float acc[8][4];
#pragma unroll
    for (int i = 0; i < 8; ++i)
#pragma unroll
        for (int t = 0; t < 4; ++t) acc[i][t] = 0.f;

    for (int c = 0; c < 8; ++c) {  // 8 chunks of 32 over K=256
        int k0 = c * KC;
        __syncthreads();  // previous chunk fully consumed
        if (tid < 128) {
            // stage one W row (j = tid), 32 floats, into k-major sW
            const float* Wsrc = (k0 < D) ? (Wl + (size_t)tid * D + k0)
                                         : (Wr + (size_t)tid * D + (k0 - D));
            float4 w[8];
#pragma unroll
            for (int q = 0; q < 8; ++q) w[q] = ((const float4*)Wsrc)[q];
#pragma unroll
            for (int q = 0; q < 8; ++q) {
                sW[4 * q + 0][tid] = w[q].x;
                sW[4 * q + 1][tid] = w[q].y;
                sW[4 * q + 2][tid] = w[q].z;
                sW[4 * q + 3][tid] = w[q].w;
            }
        } else {
            // stage A rows: 2 threads per node, 16 floats each, into k-major sA
            int t2 = tid - 128;
            int nl = t2 >> 1, half = t2 & 1;
            int n = min(n0 + nl, N - 1);
            const float* Asrc = (k0 < D) ? (Aagg + (size_t)n * D + k0)
                                         : (Ax + (size_t)n * D + (k0 - D));
            Asrc += half * 16;
            float4 a[4];
#pragma unroll
            for (int q = 0; q < 4; ++q) a[q] = ((const float4*)Asrc)[q];
#pragma unroll
            for (int q = 0; q < 4; ++q) {
                int kk = half * 16 + 4 * q;
                sA[kk + 0][nl] = a[q].x;
                sA[kk + 1][nl] = a[q].y;
                sA[kk + 2][nl] = a[q].z;
                sA[kk + 3][nl] = a[q].w;
            }
        }
        __syncthreads();

#pragma unroll 4
        for (int kk = 0; kk < KC; ++kk) {
            float4 w4 = *(const float4*)&sW[kk][jg * 4];
            float4 a0 = *(const float4*)&sA[kk][ng * 8];
            float4 a1 = *(const float4*)&sA[kk][ng * 8 + 4];
            float av[8] = {a0.x, a0.y, a0.z, a0.w, a1.x, a1.y, a1.z, a1.w};
            float wv[4] = {w4.x, w4.y, w4.z, w4.w};
#pragma unroll
            for (int i = 0; i < 8; ++i)
#pragma unroll
                for (int t = 0; t < 4; ++t) acc[i][t] += av[i] * wv[t];
        }
    }

    float4 b4 = *(const float4*)&bias[jg * 4];
    float bv[4] = {b4.x, b4.y, b4.z, b4.w};
#pragma unroll
    for (int i = 0; i < 8; ++i) {
        int n = n0 + ng * 8 + i;
        if (n < N) {
            float4 o;
            float* op = (float*)&o;
#pragma unroll
            for (int t = 0; t < 4; ++t) {
                float v = acc[i][t] + bv[t];
                if (relu) v = fmaxf(v, 0.f);
                op[t] = v;
            }
            *(float4*)&out[(size_t)n * D + jg * 4] = o;
        }
    }
}

// ---------------- launch ----------------

extern "C" void kernel_launch(void* const* d_in, const int* in_sizes, int n_in,
                              void* d_out, int out_size, void* d_ws, size_t ws_size,
                              hipStream_t stream) {
    const float* x   = (const float*)d_in[0];
    const int*   ei  = (const int*)d_in[1];
    const float* W1l = (const float*)d_in[2];
    const float* b1  = (const float*)d_in[3];
    const float* W1r = (const float*)d_in[4];
    const float* W2l = (const float*)d_in[5];
    const float* b2  = (const float*)d_in[6];
    const float* W2r = (const float*)d_in[7];
    float* out = (float*)d_out;

    int N = in_sizes[0] / D;
    int E = in_sizes[1] / 2;
    const int* src = ei;
    const int* dst = ei + E;

    char* ws = (char*)d_ws;
    size_t off = 0;
    auto take = [&](size_t bytes) -> char* {
        char* p = ws + off;
        off += (bytes + 255) & ~(size_t)255;
        return p;
    };
    int*   row_ptr = (int*)take((size_t)(N + 1) * sizeof(int));
    int*   cnt     = (int*)take((size_t)2 * N * sizeof(int));  // cnt then cur, contiguous
    int*   cur     = cnt + N;
    int*   csr     = (int*)take((size_t)E * sizeof(int));
    float* agg     = (float*)take((size_t)N * D * sizeof(float));
    float* h       = (float*)take((size_t)N * D * sizeof(float));
    (void)ws_size;
    (void)n_in;
    (void)out_size;

    hipMemsetAsync(cnt, 0, (size_t)2 * N * sizeof(int), stream);

    int eblocks = (E + 255) / 256;
    count_kernel<<<eblocks, 256, 0, stream>>>(dst, cnt, E);
    scan_kernel<<<1, 1024, 0, stream>>>(cnt, row_ptr, N);
    fill_kernel<<<eblocks, 256, 0, stream>>>(src, dst, row_ptr, cur, csr, E);

    int ablocks = (N + 3) / 4;
    int gblocks = (N + NTILE - 1) / NTILE;

    // layer 1: h = relu(mean_agg(x) @ W1l^T + b1 + x @ W1r^T)
    agg_kernel<<<ablocks, 256, 0, stream>>>(x, csr, row_ptr, agg, N);
    gemm_kernel<<<gblocks, 256, 0, stream>>>(agg, x, W1l, W1r, b1, h, N, 1);

    // layer 2: out = mean_agg(h) @ W2l^T + b2 + h @ W2r^T
    agg_kernel<<<ablocks, 256, 0, stream>>>(h, csr, row_ptr, agg, N);
    gemm_kernel<<<gblocks, 256, 0, stream>>>(agg, h, W2l, W2r, b2, out, N, 0);
}

// Round 2
// 813.951 us; speedup vs baseline: 1.1272x; 1.1272x over previous
//
#include <hip/hip_runtime.h>
#include <cstdint>
#include <cstddef>

#define D 128
#define KC 32
#define NTILE 64

// ---------------- CSR build ----------------

__global__ __launch_bounds__(256) void count_kernel(const int* __restrict__ dst,
                                                    int* __restrict__ cnt, int E) {
    int e = blockIdx.x * 256 + threadIdx.x;
    if (e < E) atomicAdd(&cnt[dst[e]], 1);
}

__global__ __launch_bounds__(1024) void scan_kernel(const int* __restrict__ cnt,
                                                    int* __restrict__ row_ptr, int N) {
    __shared__ int s[1024];
    int t = threadIdx.x;
    int chunk = (N + 1023) >> 10;
    int beg = t * chunk;
    int end = min(beg + chunk, N);
    int sum = 0;
    for (int i = beg; i < end; ++i) sum += cnt[i];
    s[t] = sum;
    __syncthreads();
    for (int off = 1; off < 1024; off <<= 1) {
        int v = (t >= off) ? s[t - off] : 0;
        __syncthreads();
        s[t] += v;
        __syncthreads();
    }
    int run = s[t] - sum;  // exclusive prefix of this thread's chunk
    for (int i = beg; i < end; ++i) { row_ptr[i] = run; run += cnt[i]; }
    if (t == 1023) row_ptr[N] = s[1023];
}

__global__ __launch_bounds__(256) void fill_kernel(const int* __restrict__ src,
                                                   const int* __restrict__ dst,
                                                   const int* __restrict__ row_ptr,
                                                   int* __restrict__ cur,
                                                   int* __restrict__ csr, int E) {
    int e = blockIdx.x * 256 + threadIdx.x;
    if (e < E) {
        int d = dst[e];
        int p = atomicAdd(&cur[d], 1);
        csr[row_ptr[d] + p] = src[e];
    }
}

// ---------------- mean aggregation: one wave per node, 8-deep MLP ----------------

__global__ __launch_bounds__(256) void agg_kernel(const float* __restrict__ xin,
                                                  const int* __restrict__ csr,
                                                  const int* __restrict__ row_ptr,
                                                  float* __restrict__ agg, int N) {
    int node = blockIdx.x * 4 + (threadIdx.x >> 6);
    if (node >= N) return;
    int lane = threadIdx.x & 63;
    int beg = row_ptr[node], end = row_ptr[node + 1];
    float ax = 0.f, ay = 0.f;
    int e = beg;
    // main loop: 8 independent row gathers in flight
    for (; e + 8 <= end; e += 8) {
        int s[8];
#pragma unroll
        for (int q = 0; q < 8; ++q) s[q] = csr[e + q];
        float2 v[8];
#pragma unroll
        for (int q = 0; q < 8; ++q)
            v[q] = ((const float2*)(xin + (size_t)s[q] * D))[lane];
#pragma unroll
        for (int q = 0; q < 8; ++q) { ax += v[q].x; ay += v[q].y; }
    }
    // 4-batch remainder
    if (e + 4 <= end) {
        int s[4];
#pragma unroll
        for (int q = 0; q < 4; ++q) s[q] = csr[e + q];
        float2 v[4];
#pragma unroll
        for (int q = 0; q < 4; ++q)
            v[q] = ((const float2*)(xin + (size_t)s[q] * D))[lane];
#pragma unroll
        for (int q = 0; q < 4; ++q) { ax += v[q].x; ay += v[q].y; }
        e += 4;
    }
    // scalar remainder (<=3)
    for (; e < end; ++e) {
        int s = csr[e];
        float2 v = ((const float2*)(xin + (size_t)s * D))[lane];
        ax += v.x;
        ay += v.y;
    }
    float inv = 1.0f / fmaxf((float)(end - beg), 1.0f);
    float2 o;
    o.x = ax * inv;
    o.y = ay * inv;
    ((float2*)(agg + (size_t)node * D))[lane] = o;
}

// ---------------- fused GEMM: out = agg @ Wl^T + xin @ Wr^T + b (+relu) ----------------
// Treated as [N,256] @ [128,256]^T with K = concat(agg-k, x-k).
// Block: 256 threads, 64 nodes x 128 outputs. Per-thread tile 8n x 4j.

__global__ __launch_bounds__(256) void gemm_kernel(const float* __restrict__ Aagg,
                                                   const float* __restrict__ Ax,
                                                   const float* __restrict__ Wl,
                                                   const float* __restrict__ Wr,
                                                   const float* __restrict__ bias,
                                                   float* __restrict__ out,
                                                   int N, int relu) {
    __shared__ float sW[KC][D];      // 16 KB, k-major
    __shared__ float sA[KC][NTILE];  // 8 KB, k-major
    int tid = threadIdx.x;
    int n0 = blockIdx.x * NTILE;
    int jg = tid & 31;   // j = jg*4 .. +3
    int ng = tid >> 5;   // nodes n0 + ng*8 .. +7

    float acc[8][4];
#pragma unroll
    for (int i = 0; i < 8; ++i)
#pragma unroll
        for (int t = 0; t < 4; ++t) acc[i][t] = 0.f;

    for (int c = 0; c < 8; ++c) {  // 8 chunks of 32 over K=256
        int k0 = c * KC;
        __syncthreads();  // previous chunk fully consumed
        if (tid < 128) {
            // stage one W row (j = tid), 32 floats, into k-major sW
            const float* Wsrc = (k0 < D) ? (Wl + (size_t)tid * D + k0)
                                         : (Wr + (size_t)tid * D + (k0 - D));
            float4 w[8];
#pragma unroll
            for (int q = 0; q < 8; ++q) w[q] = ((const float4*)Wsrc)[q];
#pragma unroll
            for (int q = 0; q < 8; ++q) {
                sW[4 * q + 0][tid] = w[q].x;
                sW[4 * q + 1][tid] = w[q].y;
                sW[4 * q + 2][tid] = w[q].z;
                sW[4 * q + 3][tid] = w[q].w;
            }
        } else {
            // stage A rows: 2 threads per node, 16 floats each, into k-major sA
            int t2 = tid - 128;
            int nl = t2 >> 1, half = t2 & 1;
            int n = min(n0 + nl, N - 1);
            const float* Asrc = (k0 < D) ? (Aagg + (size_t)n * D + k0)
                                         : (Ax + (size_t)n * D + (k0 - D));
            Asrc += half * 16;
            float4 a[4];
#pragma unroll
            for (int q = 0; q < 4; ++q) a[q] = ((const float4*)Asrc)[q];
#pragma unroll
            for (int q = 0; q < 4; ++q) {
                int kk = half * 16 + 4 * q;
                sA[kk + 0][nl] = a[q].x;
                sA[kk + 1][nl] = a[q].y;
                sA[kk + 2][nl] = a[q].z;
                sA[kk + 3][nl] = a[q].w;
            }
        }
        __syncthreads();

#pragma unroll 4
        for (int kk = 0; kk < KC; ++kk) {
            float4 w4 = *(const float4*)&sW[kk][jg * 4];
            float4 a0 = *(const float4*)&sA[kk][ng * 8];
            float4 a1 = *(const float4*)&sA[kk][ng * 8 + 4];
            float av[8] = {a0.x, a0.y, a0.z, a0.w, a1.x, a1.y, a1.z, a1.w};
            float wv[4] = {w4.x, w4.y, w4.z, w4.w};
#pragma unroll
            for (int i = 0; i < 8; ++i)
#pragma unroll
                for (int t = 0; t < 4; ++t) acc[i][t] += av[i] * wv[t];
        }
    }

    float4 b4 = *(const float4*)&bias[jg * 4];
    float bv[4] = {b4.x, b4.y, b4.z, b4.w};
#pragma unroll
    for (int i = 0; i < 8; ++i) {
        int n = n0 + ng * 8 + i;
        if (n < N) {
            float4 o;
            float* op = (float*)&o;
#pragma unroll
            for (int t = 0; t < 4; ++t) {
                float v = acc[i][t] + bv[t];
                if (relu) v = fmaxf(v, 0.f);
                op[t] = v;
            }
            *(float4*)&out[(size_t)n * D + jg * 4] = o;
        }
    }
}

// ---------------- launch ----------------

extern "C" void kernel_launch(void* const* d_in, const int* in_sizes, int n_in,
                              void* d_out, int out_size, void* d_ws, size_t ws_size,
                              hipStream_t stream) {
    const float* x   = (const float*)d_in[0];
    const int*   ei  = (const int*)d_in[1];
    const float* W1l = (const float*)d_in[2];
    const float* b1  = (const float*)d_in[3];
    const float* W1r = (const float*)d_in[4];
    const float* W2l = (const float*)d_in[5];
    const float* b2  = (const float*)d_in[6];
    const float* W2r = (const float*)d_in[7];
    float* out = (float*)d_out;

    int N = in_sizes[0] / D;
    int E = in_sizes[1] / 2;
    const int* src = ei;
    const int* dst = ei + E;

    char* ws = (char*)d_ws;
    size_t off = 0;
    auto take = [&](size_t bytes) -> char* {
        char* p = ws + off;
        off += (bytes + 255) & ~(size_t)255;
        return p;
    };
    int*   row_ptr = (int*)take((size_t)(N + 1) * sizeof(int));
    int*   cnt     = (int*)take((size_t)2 * N * sizeof(int));  // cnt then cur, contiguous
    int*   cur     = cnt + N;
    int*   csr     = (int*)take((size_t)E * sizeof(int));
    float* agg     = (float*)take((size_t)N * D * sizeof(float));
    float* h       = (float*)take((size_t)N * D * sizeof(float));
    (void)ws_size;
    (void)n_in;
    (void)out_size;

    hipMemsetAsync(cnt, 0, (size_t)2 * N * sizeof(int), stream);

    int eblocks = (E + 255) / 256;
    count_kernel<<<eblocks, 256, 0, stream>>>(dst, cnt, E);
    scan_kernel<<<1, 1024, 0, stream>>>(cnt, row_ptr, N);
    fill_kernel<<<eblocks, 256, 0, stream>>>(src, dst, row_ptr, cur, csr, E);

    int ablocks = (N + 3) / 4;
    int gblocks = (N + NTILE - 1) / NTILE;

    // layer 1: h = relu(mean_agg(x) @ W1l^T + b1 + x @ W1r^T)
    agg_kernel<<<ablocks, 256, 0, stream>>>(x, csr, row_ptr, agg, N);
    gemm_kernel<<<gblocks, 256, 0, stream>>>(agg, x, W1l, W1r, b1, h, N, 1);

    // layer 2: out = mean_agg(h) @ W2l^T + b2 + h @ W2r^T
    agg_kernel<<<ablocks, 256, 0, stream>>>(h, csr, row_ptr, agg, N);
    gemm_kernel<<<gblocks, 256, 0, stream>>>(agg, h, W2l, W2r, b2, out, N, 0);
}

// Round 3
// 659.159 us; speedup vs baseline: 1.3919x; 1.2348x over previous
//
#include <hip/hip_runtime.h>
#include <cstdint>
#include <cstddef>

#define D 128
#define KC 32
#define NTILE 64

// ---------------- CSR build ----------------

__global__ __launch_bounds__(256) void count_kernel(const int* __restrict__ dst,
                                                    int* __restrict__ cnt, int E) {
    int e = blockIdx.x * 256 + threadIdx.x;
    if (e < E) atomicAdd(&cnt[dst[e]], 1);
}

// 3-phase parallel exclusive scan of cnt[N] -> row_ptr[N+1]
__global__ __launch_bounds__(256) void scan_phase1(const int* __restrict__ cnt,
                                                   int* __restrict__ bsum, int N) {
    __shared__ int s[256];
    int t = threadIdx.x;
    int idx = blockIdx.x * 256 + t;
    s[t] = (idx < N) ? cnt[idx] : 0;
    __syncthreads();
    for (int off = 128; off > 0; off >>= 1) {
        if (t < off) s[t] += s[t + off];
        __syncthreads();
    }
    if (t == 0) bsum[blockIdx.x] = s[0];
}

__global__ __launch_bounds__(1024) void scan_phase2(int* __restrict__ bsum,
                                                    int* __restrict__ row_ptr,
                                                    int G, int N) {
    __shared__ int s[1024];
    int t = threadIdx.x;
    s[t] = (t < G) ? bsum[t] : 0;
    __syncthreads();
    for (int off = 1; off < 1024; off <<= 1) {
        int u = (t >= off) ? s[t - off] : 0;
        __syncthreads();
        s[t] += u;
        __syncthreads();
    }
    if (t < G) bsum[t] = s[t];  // inclusive block sums
    if (t == G - 1) row_ptr[N] = s[t];
}

__global__ __launch_bounds__(256) void scan_phase3(const int* __restrict__ cnt,
                                                   const int* __restrict__ bsum,
                                                   int* __restrict__ row_ptr, int N) {
    __shared__ int s[256];
    int t = threadIdx.x;
    int idx = blockIdx.x * 256 + t;
    int v = (idx < N) ? cnt[idx] : 0;
    s[t] = v;
    __syncthreads();
    for (int off = 1; off < 256; off <<= 1) {
        int u = (t >= off) ? s[t - off] : 0;
        __syncthreads();
        s[t] += u;
        __syncthreads();
    }
    int base = (blockIdx.x > 0) ? bsum[blockIdx.x - 1] : 0;
    if (idx < N) row_ptr[idx] = base + s[t] - v;
}

__global__ __launch_bounds__(256) void fill_kernel(const int* __restrict__ src,
                                                   const int* __restrict__ dst,
                                                   const int* __restrict__ row_ptr,
                                                   int* __restrict__ cur,
                                                   int* __restrict__ csr, int E) {
    int e = blockIdx.x * 256 + threadIdx.x;
    if (e < E) {
        int d = dst[e];
        int p = atomicAdd(&cur[d], 1);
        csr[row_ptr[d] + p] = src[e];
    }
}

// ---------------- mean aggregation: one wave per node, 8-deep MLP ----------------

__global__ __launch_bounds__(256) void agg_kernel(const float* __restrict__ xin,
                                                  const int* __restrict__ csr,
                                                  const int* __restrict__ row_ptr,
                                                  float* __restrict__ agg, int N) {
    int node = blockIdx.x * 4 + (threadIdx.x >> 6);
    if (node >= N) return;
    int lane = threadIdx.x & 63;
    int beg = row_ptr[node], end = row_ptr[node + 1];
    float ax = 0.f, ay = 0.f;
    int e = beg;
    // main loop: 8 independent row gathers in flight
    for (; e + 8 <= end; e += 8) {
        int s[8];
#pragma unroll
        for (int q = 0; q < 8; ++q) s[q] = csr[e + q];
        float2 v[8];
#pragma unroll
        for (int q = 0; q < 8; ++q)
            v[q] = ((const float2*)(xin + (size_t)s[q] * D))[lane];
#pragma unroll
        for (int q = 0; q < 8; ++q) { ax += v[q].x; ay += v[q].y; }
    }
    // 4-batch remainder
    if (e + 4 <= end) {
        int s[4];
#pragma unroll
        for (int q = 0; q < 4; ++q) s[q] = csr[e + q];
        float2 v[4];
#pragma unroll
        for (int q = 0; q < 4; ++q)
            v[q] = ((const float2*)(xin + (size_t)s[q] * D))[lane];
#pragma unroll
        for (int q = 0; q < 4; ++q) { ax += v[q].x; ay += v[q].y; }
        e += 4;
    }
    // scalar remainder (<=3)
    for (; e < end; ++e) {
        int s = csr[e];
        float2 v = ((const float2*)(xin + (size_t)s * D))[lane];
        ax += v.x;
        ay += v.y;
    }
    float inv = 1.0f / fmaxf((float)(end - beg), 1.0f);
    float2 o;
    o.x = ax * inv;
    o.y = ay * inv;
    ((float2*)(agg + (size_t)node * D))[lane] = o;
}

// ---------------- fused GEMM: out = agg @ Wl^T + xin @ Wr^T + b (+relu) ----------------
// Treated as [N,256] @ [128,256]^T with K = concat(agg-k, x-k).
// Block: 256 threads, 64 nodes x 128 outputs. Per-thread tile 8n x 4j.

__global__ __launch_bounds__(256) void gemm_kernel(const float* __restrict__ Aagg,
                                                   const float* __restrict__ Ax,
                                                   const float* __restrict__ Wl,
                                                   const float* __restrict__ Wr,
                                                   const float* __restrict__ bias,
                                                   float* __restrict__ out,
                                                   int N, int relu) {
    __shared__ float sW[KC][D];      // 16 KB, k-major
    __shared__ float sA[KC][NTILE];  // 8 KB, k-major
    int tid = threadIdx.x;
    int n0 = blockIdx.x * NTILE;
    int jg = tid & 31;   // j = jg*4 .. +3
    int ng = tid >> 5;   // nodes n0 + ng*8 .. +7

    float acc[8][4];
#pragma unroll
    for (int i = 0; i < 8; ++i)
#pragma unroll
        for (int t = 0; t < 4; ++t) acc[i][t] = 0.f;

    for (int c = 0; c < 8; ++c) {  // 8 chunks of 32 over K=256
        int k0 = c * KC;
        __syncthreads();  // previous chunk fully consumed
        if (tid < 128) {
            // stage one W row (j = tid), 32 floats, into k-major sW
            const float* Wsrc = (k0 < D) ? (Wl + (size_t)tid * D + k0)
                                         : (Wr + (size_t)tid * D + (k0 - D));
            float4 w[8];
#pragma unroll
            for (int q = 0; q < 8; ++q) w[q] = ((const float4*)Wsrc)[q];
#pragma unroll
            for (int q = 0; q < 8; ++q) {
                sW[4 * q + 0][tid] = w[q].x;
                sW[4 * q + 1][tid] = w[q].y;
                sW[4 * q + 2][tid] = w[q].z;
                sW[4 * q + 3][tid] = w[q].w;
            }
        } else {
            // stage A rows: 2 threads per node, 16 floats each, into k-major sA
            int t2 = tid - 128;
            int nl = t2 >> 1, half = t2 & 1;
            int n = min(n0 + nl, N - 1);
            const float* Asrc = (k0 < D) ? (Aagg + (size_t)n * D + k0)
                                         : (Ax + (size_t)n * D + (k0 - D));
            Asrc += half * 16;
            float4 a[4];
#pragma unroll
            for (int q = 0; q < 4; ++q) a[q] = ((const float4*)Asrc)[q];
#pragma unroll
            for (int q = 0; q < 4; ++q) {
                int kk = half * 16 + 4 * q;
                sA[kk + 0][nl] = a[q].x;
                sA[kk + 1][nl] = a[q].y;
                sA[kk + 2][nl] = a[q].z;
                sA[kk + 3][nl] = a[q].w;
            }
        }
        __syncthreads();

#pragma unroll 4
        for (int kk = 0; kk < KC; ++kk) {
            float4 w4 = *(const float4*)&sW[kk][jg * 4];
            float4 a0 = *(const float4*)&sA[kk][ng * 8];
            float4 a1 = *(const float4*)&sA[kk][ng * 8 + 4];
            float av[8] = {a0.x, a0.y, a0.z, a0.w, a1.x, a1.y, a1.z, a1.w};
            float wv[4] = {w4.x, w4.y, w4.z, w4.w};
#pragma unroll
            for (int i = 0; i < 8; ++i)
#pragma unroll
                for (int t = 0; t < 4; ++t) acc[i][t] += av[i] * wv[t];
        }
    }

    float4 b4 = *(const float4*)&bias[jg * 4];
    float bv[4] = {b4.x, b4.y, b4.z, b4.w};
#pragma unroll
    for (int i = 0; i < 8; ++i) {
        int n = n0 + ng * 8 + i;
        if (n < N) {
            float4 o;
            float* op = (float*)&o;
#pragma unroll
            for (int t = 0; t < 4; ++t) {
                float v = acc[i][t] + bv[t];
                if (relu) v = fmaxf(v, 0.f);
                op[t] = v;
            }
            *(float4*)&out[(size_t)n * D + jg * 4] = o;
        }
    }
}

// ---------------- launch ----------------

extern "C" void kernel_launch(void* const* d_in, const int* in_sizes, int n_in,
                              void* d_out, int out_size, void* d_ws, size_t ws_size,
                              hipStream_t stream) {
    const float* x   = (const float*)d_in[0];
    const int*   ei  = (const int*)d_in[1];
    const float* W1l = (const float*)d_in[2];
    const float* b1  = (const float*)d_in[3];
    const float* W1r = (const float*)d_in[4];
    const float* W2l = (const float*)d_in[5];
    const float* b2  = (const float*)d_in[6];
    const float* W2r = (const float*)d_in[7];
    float* out = (float*)d_out;

    int N = in_sizes[0] / D;
    int E = in_sizes[1] / 2;
    const int* src = ei;
    const int* dst = ei + E;

    char* ws = (char*)d_ws;
    size_t off = 0;
    auto take = [&](size_t bytes) -> char* {
        char* p = ws + off;
        off += (bytes + 255) & ~(size_t)255;
        return p;
    };
    int nblk256 = (N + 255) / 256;
    int*   row_ptr = (int*)take((size_t)(N + 1) * sizeof(int));
    int*   cnt     = (int*)take((size_t)2 * N * sizeof(int));  // cnt then cur, contiguous
    int*   cur     = cnt + N;
    int*   bsum    = (int*)take((size_t)nblk256 * sizeof(int));
    int*   csr     = (int*)take((size_t)E * sizeof(int));
    float* agg     = (float*)take((size_t)N * D * sizeof(float));
    float* h       = (float*)take((size_t)N * D * sizeof(float));
    (void)ws_size;
    (void)n_in;
    (void)out_size;

    hipMemsetAsync(cnt, 0, (size_t)2 * N * sizeof(int), stream);

    int eblocks = (E + 255) / 256;
    count_kernel<<<eblocks, 256, 0, stream>>>(dst, cnt, E);
    scan_phase1<<<nblk256, 256, 0, stream>>>(cnt, bsum, N);
    scan_phase2<<<1, 1024, 0, stream>>>(bsum, row_ptr, nblk256, N);
    scan_phase3<<<nblk256, 256, 0, stream>>>(cnt, bsum, row_ptr, N);
    fill_kernel<<<eblocks, 256, 0, stream>>>(src, dst, row_ptr, cur, csr, E);

    int ablocks = (N + 3) / 4;
    int gblocks = (N + NTILE - 1) / NTILE;

    // layer 1: h = relu(mean_agg(x) @ W1l^T + b1 + x @ W1r^T)
    agg_kernel<<<ablocks, 256, 0, stream>>>(x, csr, row_ptr, agg, N);
    gemm_kernel<<<gblocks, 256, 0, stream>>>(agg, x, W1l, W1r, b1, h, N, 1);

    // layer 2: out = mean_agg(h) @ W2l^T + b2 + h @ W2r^T
    agg_kernel<<<ablocks, 256, 0, stream>>>(h, csr, row_ptr, agg, N);
    gemm_kernel<<<gblocks, 256, 0, stream>>>(agg, h, W2l, W2r, b2, out, N, 0);
}

// Round 4
// 481.323 us; speedup vs baseline: 1.9061x; 1.3695x over previous
//
#include <hip/hip_runtime.h>
#include <cstdint>
#include <cstddef>

#define D 128

typedef unsigned short ushort_t;
typedef unsigned int uint_t;
typedef __attribute__((ext_vector_type(8))) short bf16x8;
typedef __attribute__((ext_vector_type(4))) float f32x4;

static __device__ __forceinline__ unsigned short f2bf(float f) {
    unsigned int u = __float_as_uint(f);
    u = (u + 0x7FFFu + ((u >> 16) & 1u)) >> 16;  // RNE
    return (unsigned short)u;
}
static __device__ __forceinline__ float bf_lo(uint_t v) {  // low 16 bits as bf16
    return __uint_as_float(v << 16);
}
static __device__ __forceinline__ float bf_hi(uint_t v) {  // high 16 bits as bf16
    return __uint_as_float(v & 0xFFFF0000u);
}

// ---------------- CSR build ----------------

__global__ __launch_bounds__(256) void count_kernel(const int* __restrict__ dst,
                                                    int* __restrict__ cnt, int E) {
    int e = blockIdx.x * 256 + threadIdx.x;
    if (e < E) atomicAdd(&cnt[dst[e]], 1);
}

__global__ __launch_bounds__(256) void scan_phase1(const int* __restrict__ cnt,
                                                   int* __restrict__ bsum, int N) {
    __shared__ int s[256];
    int t = threadIdx.x;
    int idx = blockIdx.x * 256 + t;
    s[t] = (idx < N) ? cnt[idx] : 0;
    __syncthreads();
    for (int off = 128; off > 0; off >>= 1) {
        if (t < off) s[t] += s[t + off];
        __syncthreads();
    }
    if (t == 0) bsum[blockIdx.x] = s[0];
}

__global__ __launch_bounds__(1024) void scan_phase2(int* __restrict__ bsum,
                                                    int* __restrict__ row_ptr,
                                                    int G, int N) {
    __shared__ int s[1024];
    int t = threadIdx.x;
    s[t] = (t < G) ? bsum[t] : 0;
    __syncthreads();
    for (int off = 1; off < 1024; off <<= 1) {
        int u = (t >= off) ? s[t - off] : 0;
        __syncthreads();
        s[t] += u;
        __syncthreads();
    }
    if (t < G) bsum[t] = s[t];
    if (t == G - 1) row_ptr[N] = s[t];
}

__global__ __launch_bounds__(256) void scan_phase3(const int* __restrict__ cnt,
                                                   const int* __restrict__ bsum,
                                                   int* __restrict__ row_ptr, int N) {
    __shared__ int s[256];
    int t = threadIdx.x;
    int idx = blockIdx.x * 256 + t;
    int v = (idx < N) ? cnt[idx] : 0;
    s[t] = v;
    __syncthreads();
    for (int off = 1; off < 256; off <<= 1) {
        int u = (t >= off) ? s[t - off] : 0;
        __syncthreads();
        s[t] += u;
        __syncthreads();
    }
    int base = (blockIdx.x > 0) ? bsum[blockIdx.x - 1] : 0;
    if (idx < N) row_ptr[idx] = base + s[t] - v;
}

__global__ __launch_bounds__(256) void fill_kernel(const int* __restrict__ src,
                                                   const int* __restrict__ dst,
                                                   const int* __restrict__ row_ptr,
                                                   int* __restrict__ cur,
                                                   int* __restrict__ csr, int E) {
    int e = blockIdx.x * 256 + threadIdx.x;
    if (e < E) {
        int d = dst[e];
        int p = atomicAdd(&cur[d], 1);
        csr[row_ptr[d] + p] = src[e];
    }
}

// ---------------- fp32 -> bf16 casts ----------------

// 8 elements per thread
__global__ __launch_bounds__(256) void cast_x_kernel(const float* __restrict__ src,
                                                     ushort_t* __restrict__ dst,
                                                     long n) {
    long i = ((long)blockIdx.x * 256 + threadIdx.x) * 8;
    if (i >= n) return;
    float4 a = *(const float4*)(src + i);
    float4 b = *(const float4*)(src + i + 4);
    uint4 o;
    o.x = (uint_t)f2bf(a.x) | ((uint_t)f2bf(a.y) << 16);
    o.y = (uint_t)f2bf(a.z) | ((uint_t)f2bf(a.w) << 16);
    o.z = (uint_t)f2bf(b.x) | ((uint_t)f2bf(b.y) << 16);
    o.w = (uint_t)f2bf(b.z) | ((uint_t)f2bf(b.w) << 16);
    *(uint4*)(dst + i) = o;
}

// four 128x128 weight matrices, blockIdx.y selects
__global__ __launch_bounds__(256) void cast_w_kernel(const float* __restrict__ s0,
                                                     const float* __restrict__ s1,
                                                     const float* __restrict__ s2,
                                                     const float* __restrict__ s3,
                                                     ushort_t* __restrict__ d0,
                                                     ushort_t* __restrict__ d1,
                                                     ushort_t* __restrict__ d2,
                                                     ushort_t* __restrict__ d3) {
    const float* s = (blockIdx.y == 0) ? s0 : (blockIdx.y == 1) ? s1
                   : (blockIdx.y == 2) ? s2 : s3;
    ushort_t* d = (blockIdx.y == 0) ? d0 : (blockIdx.y == 1) ? d1
                : (blockIdx.y == 2) ? d2 : d3;
    long i = ((long)blockIdx.x * 256 + threadIdx.x) * 8;  // 16384 elems, 8 blocks
    float4 a = *(const float4*)(s + i);
    float4 b = *(const float4*)(s + i + 4);
    uint4 o;
    o.x = (uint_t)f2bf(a.x) | ((uint_t)f2bf(a.y) << 16);
    o.y = (uint_t)f2bf(a.z) | ((uint_t)f2bf(a.w) << 16);
    o.z = (uint_t)f2bf(b.x) | ((uint_t)f2bf(b.y) << 16);
    o.w = (uint_t)f2bf(b.z) | ((uint_t)f2bf(b.w) << 16);
    *(uint4*)(d + i) = o;
}

// ---------------- mean aggregation over bf16 rows ----------------
// one wave per node; lane covers elements 2*lane, 2*lane+1 (uint gather = 256 B/row)

__global__ __launch_bounds__(256) void agg_b_kernel(const ushort_t* __restrict__ xin,
                                                    const int* __restrict__ csr,
                                                    const int* __restrict__ row_ptr,
                                                    ushort_t* __restrict__ aggb, int N) {
    int node = blockIdx.x * 4 + (threadIdx.x >> 6);
    if (node >= N) return;
    int lane = threadIdx.x & 63;
    int beg = row_ptr[node], end = row_ptr[node + 1];
    float ax = 0.f, ay = 0.f;
    int e = beg;
    for (; e + 8 <= end; e += 8) {
        int s[8];
#pragma unroll
        for (int q = 0; q < 8; ++q) s[q] = csr[e + q];
        uint_t v[8];
#pragma unroll
        for (int q = 0; q < 8; ++q)
            v[q] = ((const uint_t*)(xin + (size_t)s[q] * D))[lane];
#pragma unroll
        for (int q = 0; q < 8; ++q) { ax += bf_lo(v[q]); ay += bf_hi(v[q]); }
    }
    if (e + 4 <= end) {
        int s[4];
#pragma unroll
        for (int q = 0; q < 4; ++q) s[q] = csr[e + q];
        uint_t v[4];
#pragma unroll
        for (int q = 0; q < 4; ++q)
            v[q] = ((const uint_t*)(xin + (size_t)s[q] * D))[lane];
#pragma unroll
        for (int q = 0; q < 4; ++q) { ax += bf_lo(v[q]); ay += bf_hi(v[q]); }
        e += 4;
    }
    for (; e < end; ++e) {
        uint_t v = ((const uint_t*)(xin + (size_t)csr[e] * D))[lane];
        ax += bf_lo(v);
        ay += bf_hi(v);
    }
    float inv = 1.0f / fmaxf((float)(end - beg), 1.0f);
    uint_t o = (uint_t)f2bf(ax * inv) | ((uint_t)f2bf(ay * inv) << 16);
    ((uint_t*)(aggb + (size_t)node * D))[lane] = o;
}

// ---------------- MFMA GEMM: out = [aggb|xinb] @ [Wl|Wr]^T + bias ----------------
// Block: 256 thr = 4 waves; tile 64 nodes x 128 cols.
// Wave: mg = wave&1 (32 nodes), cg = wave>>1 (64 cols) -> 2x4 acc frags of 16x16.
// A-frag: lane holds A[m=lane&15][k = quad*8 + 0..7]; B-frag: W row (col j), same k pattern.
// C/D: col = lane&15, row = quad*4 + reg.

__global__ __launch_bounds__(256) void gemm_mfma(const ushort_t* __restrict__ Aagg,
                                                 const ushort_t* __restrict__ Ax,
                                                 const ushort_t* __restrict__ Wl,
                                                 const ushort_t* __restrict__ Wr,
                                                 const float* __restrict__ bias,
                                                 ushort_t* __restrict__ out_bf,
                                                 float* __restrict__ out_f32,
                                                 int N, int relu_bf) {
    int tid = threadIdx.x;
    int wave = tid >> 6, lane = tid & 63;
    int quad = lane >> 4, l15 = lane & 15;
    int mg = wave & 1, cg = wave >> 1;
    int n0 = blockIdx.x * 64;

    f32x4 acc[2][4];
#pragma unroll
    for (int mt = 0; mt < 2; ++mt)
#pragma unroll
        for (int nt = 0; nt < 4; ++nt) acc[mt][nt] = (f32x4){0.f, 0.f, 0.f, 0.f};

    int r0 = min(n0 + mg * 32 + l15, N - 1);
    int r1 = min(n0 + mg * 32 + 16 + l15, N - 1);
    int jb = cg * 64 + l15;  // col for b-frags (nt adds 16 each)

#pragma unroll
    for (int c = 0; c < 8; ++c) {
        const ushort_t* Ab = (c < 4) ? Aagg : Ax;
        const ushort_t* Wb = (c < 4) ? Wl : Wr;
        int koff = (c & 3) * 32 + quad * 8;
        bf16x8 a0 = *(const bf16x8*)(Ab + (size_t)r0 * D + koff);
        bf16x8 a1 = *(const bf16x8*)(Ab + (size_t)r1 * D + koff);
        bf16x8 b0 = *(const bf16x8*)(Wb + (size_t)(jb + 0) * D + koff);
        bf16x8 b1 = *(const bf16x8*)(Wb + (size_t)(jb + 16) * D + koff);
        bf16x8 b2 = *(const bf16x8*)(Wb + (size_t)(jb + 32) * D + koff);
        bf16x8 b3 = *(const bf16x8*)(Wb + (size_t)(jb + 48) * D + koff);
        acc[0][0] = __builtin_amdgcn_mfma_f32_16x16x32_bf16(a0, b0, acc[0][0], 0, 0, 0);
        acc[0][1] = __builtin_amdgcn_mfma_f32_16x16x32_bf16(a0, b1, acc[0][1], 0, 0, 0);
        acc[0][2] = __builtin_amdgcn_mfma_f32_16x16x32_bf16(a0, b2, acc[0][2], 0, 0, 0);
        acc[0][3] = __builtin_amdgcn_mfma_f32_16x16x32_bf16(a0, b3, acc[0][3], 0, 0, 0);
        acc[1][0] = __builtin_amdgcn_mfma_f32_16x16x32_bf16(a1, b0, acc[1][0], 0, 0, 0);
        acc[1][1] = __builtin_amdgcn_mfma_f32_16x16x32_bf16(a1, b1, acc[1][1], 0, 0, 0);
        acc[1][2] = __builtin_amdgcn_mfma_f32_16x16x32_bf16(a1, b2, acc[1][2], 0, 0, 0);
        acc[1][3] = __builtin_amdgcn_mfma_f32_16x16x32_bf16(a1, b3, acc[1][3], 0, 0, 0);
    }

#pragma unroll
    for (int mt = 0; mt < 2; ++mt) {
#pragma unroll
        for (int nt = 0; nt < 4; ++nt) {
            int col = cg * 64 + nt * 16 + l15;
            float bv = bias[col];
#pragma unroll
            for (int reg = 0; reg < 4; ++reg) {
                int row = n0 + mg * 32 + mt * 16 + quad * 4 + reg;
                if (row < N) {
                    float v = acc[mt][nt][reg] + bv;
                    if (relu_bf) {
                        v = fmaxf(v, 0.f);
                        out_bf[(size_t)row * D + col] = f2bf(v);
                    } else {
                        out_f32[(size_t)row * D + col] = v;
                    }
                }
            }
        }
    }
}

// ---------------- launch ----------------

extern "C" void kernel_launch(void* const* d_in, const int* in_sizes, int n_in,
                              void* d_out, int out_size, void* d_ws, size_t ws_size,
                              hipStream_t stream) {
    const float* x   = (const float*)d_in[0];
    const int*   ei  = (const int*)d_in[1];
    const float* W1l = (const float*)d_in[2];
    const float* b1  = (const float*)d_in[3];
    const float* W1r = (const float*)d_in[4];
    const float* W2l = (const float*)d_in[5];
    const float* b2  = (const float*)d_in[6];
    const float* W2r = (const float*)d_in[7];
    float* out = (float*)d_out;

    int N = in_sizes[0] / D;
    int E = in_sizes[1] / 2;
    const int* src = ei;
    const int* dst = ei + E;

    char* ws = (char*)d_ws;
    size_t off = 0;
    auto take = [&](size_t bytes) -> char* {
        char* p = ws + off;
        off += (bytes + 255) & ~(size_t)255;
        return p;
    };
    int nblk256 = (N + 255) / 256;
    int*      row_ptr = (int*)take((size_t)(N + 1) * sizeof(int));
    int*      cnt     = (int*)take((size_t)2 * N * sizeof(int));
    int*      cur     = cnt + N;
    int*      bsum    = (int*)take((size_t)nblk256 * sizeof(int));
    int*      csr     = (int*)take((size_t)E * sizeof(int));
    ushort_t* xb      = (ushort_t*)take((size_t)N * D * sizeof(ushort_t));
    ushort_t* hb      = (ushort_t*)take((size_t)N * D * sizeof(ushort_t));
    ushort_t* aggb    = (ushort_t*)take((size_t)N * D * sizeof(ushort_t));
    ushort_t* W1lb    = (ushort_t*)take((size_t)D * D * sizeof(ushort_t));
    ushort_t* W1rb    = (ushort_t*)take((size_t)D * D * sizeof(ushort_t));
    ushort_t* W2lb    = (ushort_t*)take((size_t)D * D * sizeof(ushort_t));
    ushort_t* W2rb    = (ushort_t*)take((size_t)D * D * sizeof(ushort_t));
    (void)ws_size;
    (void)n_in;
    (void)out_size;

    hipMemsetAsync(cnt, 0, (size_t)2 * N * sizeof(int), stream);

    int eblocks = (E + 255) / 256;
    count_kernel<<<eblocks, 256, 0, stream>>>(dst, cnt, E);
    scan_phase1<<<nblk256, 256, 0, stream>>>(cnt, bsum, N);
    scan_phase2<<<1, 1024, 0, stream>>>(bsum, row_ptr, nblk256, N);
    scan_phase3<<<nblk256, 256, 0, stream>>>(cnt, bsum, row_ptr, N);
    fill_kernel<<<eblocks, 256, 0, stream>>>(src, dst, row_ptr, cur, csr, E);

    long nx = (long)N * D;
    cast_x_kernel<<<(int)((nx / 8 + 255) / 256), 256, 0, stream>>>(x, xb, nx);
    cast_w_kernel<<<dim3(8, 4), 256, 0, stream>>>(W1l, W1r, W2l, W2r,
                                                  W1lb, W1rb, W2lb, W2rb);

    int ablocks = (N + 3) / 4;
    int gblocks = (N + 63) / 64;

    // layer 1: hb = bf16(relu(mean_agg(xb) @ W1l^T + b1 + xb @ W1r^T))
    agg_b_kernel<<<ablocks, 256, 0, stream>>>(xb, csr, row_ptr, aggb, N);
    gemm_mfma<<<gblocks, 256, 0, stream>>>(aggb, xb, W1lb, W1rb, b1, hb, nullptr, N, 1);

    // layer 2: out = mean_agg(hb) @ W2l^T + b2 + hb @ W2r^T   (fp32 out)
    agg_b_kernel<<<ablocks, 256, 0, stream>>>(hb, csr, row_ptr, aggb, N);
    gemm_mfma<<<gblocks, 256, 0, stream>>>(aggb, hb, W2lb, W2rb, b2, nullptr, out, N, 0);
}

// Round 5
// 386.064 us; speedup vs baseline: 2.3764x; 1.2467x over previous
//
#include <hip/hip_runtime.h>
#include <cstdint>
#include <cstddef>

#define D 128

typedef unsigned short ushort_t;
typedef unsigned int uint_t;
typedef __attribute__((ext_vector_type(8))) short bf16x8;
typedef __attribute__((ext_vector_type(4))) float f32x4;

static __device__ __forceinline__ unsigned short f2bf(float f) {
    unsigned int u = __float_as_uint(f);
    u = (u + 0x7FFFu + ((u >> 16) & 1u)) >> 16;  // RNE
    return (unsigned short)u;
}
static __device__ __forceinline__ float bf_lo(uint_t v) {
    return __uint_as_float(v << 16);
}
static __device__ __forceinline__ float bf_hi(uint_t v) {
    return __uint_as_float(v & 0xFFFF0000u);
}

// ================= CSR build: two-level counting sort =================
// Buckets of 256 nodes (bkt = dst>>8). NB = ceil(N/256) <= 512.
// row_ptr[b*256 + t] = boff[b] + local_scan  -- no global per-node count/scan needed.

// k1: global bucket histogram via LDS
__global__ __launch_bounds__(256) void bkt_hist(const int* __restrict__ dst,
                                                int* __restrict__ bhist, int E) {
    __shared__ int lh[512];
    int t = threadIdx.x;
    lh[t] = 0;
    lh[t + 256] = 0;
    __syncthreads();
    int base = blockIdx.x * 4096;
#pragma unroll
    for (int i = 0; i < 16; ++i) {
        int e = base + i * 256 + t;
        if (e < E) atomicAdd(&lh[dst[e] >> 8], 1);
    }
    __syncthreads();
    if (lh[t]) atomicAdd(&bhist[t], lh[t]);
    if (lh[t + 256]) atomicAdd(&bhist[t + 256], lh[t + 256]);
}

// k2: scan 512 bucket counts -> boff (exclusive), init bcur, row_ptr[N]=E
__global__ __launch_bounds__(512) void bkt_scan(const int* __restrict__ bhist,
                                                int* __restrict__ boff,
                                                int* __restrict__ bcur,
                                                int* __restrict__ row_ptr,
                                                int N, int E) {
    __shared__ int s[512];
    int t = threadIdx.x;
    int v = bhist[t];
    s[t] = v;
    __syncthreads();
    for (int off = 1; off < 512; off <<= 1) {
        int u = (t >= off) ? s[t - off] : 0;
        __syncthreads();
        s[t] += u;
        __syncthreads();
    }
    int ex = s[t] - v;
    boff[t] = ex;
    bcur[t] = ex;
    if (t == 511) boff[512] = s[511];
    if (t == 0) row_ptr[N] = E;
}

// k3: scatter edges into bucket regions, block-grouped for write locality.
// record = src | (dlocal<<20)  (src < 2^20, dlocal < 256)
__global__ __launch_bounds__(256) void bkt_scatter(const int* __restrict__ src,
                                                   const int* __restrict__ dst,
                                                   int* __restrict__ bcur,
                                                   int* __restrict__ ebuf, int E) {
    __shared__ int lh[512];
    __shared__ int gb[512];
    int t = threadIdx.x;
    lh[t] = 0;
    lh[t + 256] = 0;
    __syncthreads();
    int base = blockIdx.x * 4096;
    unsigned pk[16];  // rank<<17 | bkt<<8 | dlocal
#pragma unroll
    for (int i = 0; i < 16; ++i) {
        int e = base + i * 256 + t;
        unsigned p = 0xFFFFFFFFu;
        if (e < E) {
            int d = dst[e];
            int bkt = d >> 8;
            int r = atomicAdd(&lh[bkt], 1);
            p = ((unsigned)r << 17) | ((unsigned)bkt << 8) | (unsigned)(d & 255);
        }
        pk[i] = p;
    }
    __syncthreads();
    if (lh[t]) gb[t] = atomicAdd(&bcur[t], lh[t]);
    if (lh[t + 256]) gb[t + 256] = atomicAdd(&bcur[t + 256], lh[t + 256]);
    __syncthreads();
#pragma unroll
    for (int i = 0; i < 16; ++i) {
        int e = base + i * 256 + t;
        if (e < E) {
            unsigned p = pk[i];
            int bkt = (p >> 8) & 511;
            int r = (int)(p >> 17);
            ebuf[gb[bkt] + r] = src[e] | ((int)(p & 255) << 20);
        }
    }
}

// k4: one block per bucket: local counts -> local scan -> row_ptr + csr segment.
// csr window (~16KB) is block-private -> perfect write combining.
__global__ __launch_bounds__(256) void bkt_build(const int* __restrict__ ebuf,
                                                 const int* __restrict__ boff,
                                                 int* __restrict__ row_ptr,
                                                 int* __restrict__ csr, int N) {
    __shared__ int lcnt[256];
    __shared__ int lofs[256];
    __shared__ int lcur[256];
    int t = threadIdx.x;
    int b = blockIdx.x;
    int base = b << 8;
    int ebeg = boff[b], eend = boff[b + 1];
    lcnt[t] = 0;
    __syncthreads();
    for (int e = ebeg + t; e < eend; e += 256)
        atomicAdd(&lcnt[((unsigned)ebuf[e]) >> 20], 1);
    __syncthreads();
    int v = lcnt[t];
    lofs[t] = v;
    __syncthreads();
    for (int off = 1; off < 256; off <<= 1) {
        int u = (t >= off) ? lofs[t - off] : 0;
        __syncthreads();
        lofs[t] += u;
        __syncthreads();
    }
    int ex = lofs[t] - v;  // exclusive
    __syncthreads();
    lofs[t] = ex;
    lcur[t] = 0;
    if (base + t < N) row_ptr[base + t] = ebeg + ex;
    __syncthreads();
    for (int e = ebeg + t; e < eend; e += 256) {
        int u = ebuf[e];
        int d = ((unsigned)u) >> 20;
        int r = atomicAdd(&lcur[d], 1);
        csr[ebeg + lofs[d] + r] = u & 0xFFFFF;
    }
}

// ================= fp32 -> bf16 casts =================

__global__ __launch_bounds__(256) void cast_x_kernel(const float* __restrict__ src,
                                                     ushort_t* __restrict__ dst,
                                                     long n) {
    long i = ((long)blockIdx.x * 256 + threadIdx.x) * 8;
    if (i >= n) return;
    float4 a = *(const float4*)(src + i);
    float4 b = *(const float4*)(src + i + 4);
    uint4 o;
    o.x = (uint_t)f2bf(a.x) | ((uint_t)f2bf(a.y) << 16);
    o.y = (uint_t)f2bf(a.z) | ((uint_t)f2bf(a.w) << 16);
    o.z = (uint_t)f2bf(b.x) | ((uint_t)f2bf(b.y) << 16);
    o.w = (uint_t)f2bf(b.z) | ((uint_t)f2bf(b.w) << 16);
    *(uint4*)(dst + i) = o;
}

__global__ __launch_bounds__(256) void cast_w_kernel(const float* __restrict__ s0,
                                                     const float* __restrict__ s1,
                                                     const float* __restrict__ s2,
                                                     const float* __restrict__ s3,
                                                     ushort_t* __restrict__ d0,
                                                     ushort_t* __restrict__ d1,
                                                     ushort_t* __restrict__ d2,
                                                     ushort_t* __restrict__ d3) {
    const float* s = (blockIdx.y == 0) ? s0 : (blockIdx.y == 1) ? s1
                   : (blockIdx.y == 2) ? s2 : s3;
    ushort_t* d = (blockIdx.y == 0) ? d0 : (blockIdx.y == 1) ? d1
                : (blockIdx.y == 2) ? d2 : d3;
    long i = ((long)blockIdx.x * 256 + threadIdx.x) * 8;
    float4 a = *(const float4*)(s + i);
    float4 b = *(const float4*)(s + i + 4);
    uint4 o;
    o.x = (uint_t)f2bf(a.x) | ((uint_t)f2bf(a.y) << 16);
    o.y = (uint_t)f2bf(a.z) | ((uint_t)f2bf(a.w) << 16);
    o.z = (uint_t)f2bf(b.x) | ((uint_t)f2bf(b.y) << 16);
    o.w = (uint_t)f2bf(b.z) | ((uint_t)f2bf(b.w) << 16);
    *(uint4*)(d + i) = o;
}

// ================= mean aggregation over bf16 rows =================

__global__ __launch_bounds__(256) void agg_b_kernel(const ushort_t* __restrict__ xin,
                                                    const int* __restrict__ csr,
                                                    const int* __restrict__ row_ptr,
                                                    ushort_t* __restrict__ aggb, int N) {
    int node = blockIdx.x * 4 + (threadIdx.x >> 6);
    if (node >= N) return;
    int lane = threadIdx.x & 63;
    int beg = row_ptr[node], end = row_ptr[node + 1];
    float ax = 0.f, ay = 0.f;
    int e = beg;
    for (; e + 8 <= end; e += 8) {
        int s[8];
#pragma unroll
        for (int q = 0; q < 8; ++q) s[q] = csr[e + q];
        uint_t v[8];
#pragma unroll
        for (int q = 0; q < 8; ++q)
            v[q] = ((const uint_t*)(xin + (size_t)s[q] * D))[lane];
#pragma unroll
        for (int q = 0; q < 8; ++q) { ax += bf_lo(v[q]); ay += bf_hi(v[q]); }
    }
    if (e + 4 <= end) {
        int s[4];
#pragma unroll
        for (int q = 0; q < 4; ++q) s[q] = csr[e + q];
        uint_t v[4];
#pragma unroll
        for (int q = 0; q < 4; ++q)
            v[q] = ((const uint_t*)(xin + (size_t)s[q] * D))[lane];
#pragma unroll
        for (int q = 0; q < 4; ++q) { ax += bf_lo(v[q]); ay += bf_hi(v[q]); }
        e += 4;
    }
    for (; e < end; ++e) {
        uint_t v = ((const uint_t*)(xin + (size_t)csr[e] * D))[lane];
        ax += bf_lo(v);
        ay += bf_hi(v);
    }
    float inv = 1.0f / fmaxf((float)(end - beg), 1.0f);
    uint_t o = (uint_t)f2bf(ax * inv) | ((uint_t)f2bf(ay * inv) << 16);
    ((uint_t*)(aggb + (size_t)node * D))[lane] = o;
}

// ================= MFMA GEMM: out = [aggb|xinb] @ [Wl|Wr]^T + bias =================

__global__ __launch_bounds__(256) void gemm_mfma(const ushort_t* __restrict__ Aagg,
                                                 const ushort_t* __restrict__ Ax,
                                                 const ushort_t* __restrict__ Wl,
                                                 const ushort_t* __restrict__ Wr,
                                                 const float* __restrict__ bias,
                                                 ushort_t* __restrict__ out_bf,
                                                 float* __restrict__ out_f32,
                                                 int N, int relu_bf) {
    int tid = threadIdx.x;
    int wave = tid >> 6, lane = tid & 63;
    int quad = lane >> 4, l15 = lane & 15;
    int mg = wave & 1, cg = wave >> 1;
    int n0 = blockIdx.x * 64;

    f32x4 acc[2][4];
#pragma unroll
    for (int mt = 0; mt < 2; ++mt)
#pragma unroll
        for (int nt = 0; nt < 4; ++nt) acc[mt][nt] = (f32x4){0.f, 0.f, 0.f, 0.f};

    int r0 = min(n0 + mg * 32 + l15, N - 1);
    int r1 = min(n0 + mg * 32 + 16 + l15, N - 1);
    int jb = cg * 64 + l15;

#pragma unroll
    for (int c = 0; c < 8; ++c) {
        const ushort_t* Ab = (c < 4) ? Aagg : Ax;
        const ushort_t* Wb = (c < 4) ? Wl : Wr;
        int koff = (c & 3) * 32 + quad * 8;
        bf16x8 a0 = *(const bf16x8*)(Ab + (size_t)r0 * D + koff);
        bf16x8 a1 = *(const bf16x8*)(Ab + (size_t)r1 * D + koff);
        bf16x8 b0 = *(const bf16x8*)(Wb + (size_t)(jb + 0) * D + koff);
        bf16x8 b1 = *(const bf16x8*)(Wb + (size_t)(jb + 16) * D + koff);
        bf16x8 b2 = *(const bf16x8*)(Wb + (size_t)(jb + 32) * D + koff);
        bf16x8 b3 = *(const bf16x8*)(Wb + (size_t)(jb + 48) * D + koff);
        acc[0][0] = __builtin_amdgcn_mfma_f32_16x16x32_bf16(a0, b0, acc[0][0], 0, 0, 0);
        acc[0][1] = __builtin_amdgcn_mfma_f32_16x16x32_bf16(a0, b1, acc[0][1], 0, 0, 0);
        acc[0][2] = __builtin_amdgcn_mfma_f32_16x16x32_bf16(a0, b2, acc[0][2], 0, 0, 0);
        acc[0][3] = __builtin_amdgcn_mfma_f32_16x16x32_bf16(a0, b3, acc[0][3], 0, 0, 0);
        acc[1][0] = __builtin_amdgcn_mfma_f32_16x16x32_bf16(a1, b0, acc[1][0], 0, 0, 0);
        acc[1][1] = __builtin_amdgcn_mfma_f32_16x16x32_bf16(a1, b1, acc[1][1], 0, 0, 0);
        acc[1][2] = __builtin_amdgcn_mfma_f32_16x16x32_bf16(a1, b2, acc[1][2], 0, 0, 0);
        acc[1][3] = __builtin_amdgcn_mfma_f32_16x16x32_bf16(a1, b3, acc[1][3], 0, 0, 0);
    }

#pragma unroll
    for (int mt = 0; mt < 2; ++mt) {
#pragma unroll
        for (int nt = 0; nt < 4; ++nt) {
            int col = cg * 64 + nt * 16 + l15;
            float bv = bias[col];
#pragma unroll
            for (int reg = 0; reg < 4; ++reg) {
                int row = n0 + mg * 32 + mt * 16 + quad * 4 + reg;
                if (row < N) {
                    float v = acc[mt][nt][reg] + bv;
                    if (relu_bf) {
                        v = fmaxf(v, 0.f);
                        out_bf[(size_t)row * D + col] = f2bf(v);
                    } else {
                        out_f32[(size_t)row * D + col] = v;
                    }
                }
            }
        }
    }
}

// ================= launch =================

extern "C" void kernel_launch(void* const* d_in, const int* in_sizes, int n_in,
                              void* d_out, int out_size, void* d_ws, size_t ws_size,
                              hipStream_t stream) {
    const float* x   = (const float*)d_in[0];
    const int*   ei  = (const int*)d_in[1];
    const float* W1l = (const float*)d_in[2];
    const float* b1  = (const float*)d_in[3];
    const float* W1r = (const float*)d_in[4];
    const float* W2l = (const float*)d_in[5];
    const float* b2  = (const float*)d_in[6];
    const float* W2r = (const float*)d_in[7];
    float* out = (float*)d_out;

    int N = in_sizes[0] / D;
    int E = in_sizes[1] / 2;
    const int* src = ei;
    const int* dst = ei + E;

    char* ws = (char*)d_ws;
    size_t off = 0;
    auto take = [&](size_t bytes) -> char* {
        char* p = ws + off;
        off += (bytes + 255) & ~(size_t)255;
        return p;
    };
    int*      row_ptr = (int*)take((size_t)(N + 1) * sizeof(int));
    int*      bhist   = (int*)take((size_t)(512 + 512 + 513) * sizeof(int));
    int*      bcur    = bhist + 512;
    int*      boff    = bhist + 1024;
    int*      ebuf    = (int*)take((size_t)E * sizeof(int));
    int*      csr     = (int*)take((size_t)E * sizeof(int));
    ushort_t* xb      = (ushort_t*)take((size_t)N * D * sizeof(ushort_t));
    ushort_t* hb      = (ushort_t*)take((size_t)N * D * sizeof(ushort_t));
    ushort_t* aggb    = (ushort_t*)take((size_t)N * D * sizeof(ushort_t));
    ushort_t* W1lb    = (ushort_t*)take((size_t)D * D * sizeof(ushort_t));
    ushort_t* W1rb    = (ushort_t*)take((size_t)D * D * sizeof(ushort_t));
    ushort_t* W2lb    = (ushort_t*)take((size_t)D * D * sizeof(ushort_t));
    ushort_t* W2rb    = (ushort_t*)take((size_t)D * D * sizeof(ushort_t));
    (void)ws_size;
    (void)n_in;
    (void)out_size;

    // zero bhist + bcur (boff fully written by bkt_scan)
    hipMemsetAsync(bhist, 0, 1024 * sizeof(int), stream);

    int NB = (N + 255) / 256;       // buckets (<=512)
    int EB = (E + 4095) / 4096;     // edge chunks

    bkt_hist<<<EB, 256, 0, stream>>>(dst, bhist, E);
    bkt_scan<<<1, 512, 0, stream>>>(bhist, boff, bcur, row_ptr, N, E);
    bkt_scatter<<<EB, 256, 0, stream>>>(src, dst, bcur, ebuf, E);
    bkt_build<<<NB, 256, 0, stream>>>(ebuf, boff, row_ptr, csr, N);

    long nx = (long)N * D;
    cast_x_kernel<<<(int)((nx / 8 + 255) / 256), 256, 0, stream>>>(x, xb, nx);
    cast_w_kernel<<<dim3(8, 4), 256, 0, stream>>>(W1l, W1r, W2l, W2r,
                                                  W1lb, W1rb, W2lb, W2rb);

    int ablocks = (N + 3) / 4;
    int gblocks = (N + 63) / 64;

    agg_b_kernel<<<ablocks, 256, 0, stream>>>(xb, csr, row_ptr, aggb, N);
    gemm_mfma<<<gblocks, 256, 0, stream>>>(aggb, xb, W1lb, W1rb, b1, hb, nullptr, N, 1);

    agg_b_kernel<<<ablocks, 256, 0, stream>>>(hb, csr, row_ptr, aggb, N);
    gemm_mfma<<<gblocks, 256, 0, stream>>>(aggb, hb, W2lb, W2rb, b2, nullptr, out, N, 0);
}

// Round 6
// 382.897 us; speedup vs baseline: 2.3961x; 1.0083x over previous
//
#include <hip/hip_runtime.h>
#include <cstdint>
#include <cstddef>

#define D 128

typedef unsigned short ushort_t;
typedef unsigned int uint_t;
typedef __attribute__((ext_vector_type(8))) short bf16x8;
typedef __attribute__((ext_vector_type(4))) float f32x4;

static __device__ __forceinline__ unsigned short f2bf(float f) {
    unsigned int u = __float_as_uint(f);
    u = (u + 0x7FFFu + ((u >> 16) & 1u)) >> 16;  // RNE
    return (unsigned short)u;
}
static __device__ __forceinline__ float bf_lo(uint_t v) {
    return __uint_as_float(v << 16);
}
static __device__ __forceinline__ float bf_hi(uint_t v) {
    return __uint_as_float(v & 0xFFFF0000u);
}

// ================= CSR build: two-level counting sort =================

__global__ __launch_bounds__(256) void bkt_hist(const int* __restrict__ dst,
                                                int* __restrict__ bhist, int E) {
    __shared__ int lh[512];
    int t = threadIdx.x;
    lh[t] = 0;
    lh[t + 256] = 0;
    __syncthreads();
    int base = blockIdx.x * 4096;
#pragma unroll
    for (int i = 0; i < 16; ++i) {
        int e = base + i * 256 + t;
        if (e < E) atomicAdd(&lh[dst[e] >> 8], 1);
    }
    __syncthreads();
    if (lh[t]) atomicAdd(&bhist[t], lh[t]);
    if (lh[t + 256]) atomicAdd(&bhist[t + 256], lh[t + 256]);
}

__global__ __launch_bounds__(512) void bkt_scan(const int* __restrict__ bhist,
                                                int* __restrict__ boff,
                                                int* __restrict__ bcur,
                                                int* __restrict__ row_ptr,
                                                int N, int E) {
    __shared__ int s[512];
    int t = threadIdx.x;
    int v = bhist[t];
    s[t] = v;
    __syncthreads();
    for (int off = 1; off < 512; off <<= 1) {
        int u = (t >= off) ? s[t - off] : 0;
        __syncthreads();
        s[t] += u;
        __syncthreads();
    }
    int ex = s[t] - v;
    boff[t] = ex;
    bcur[t] = ex;
    if (t == 511) boff[512] = s[511];
    if (t == 0) row_ptr[N] = E;
}

__global__ __launch_bounds__(256) void bkt_scatter(const int* __restrict__ src,
                                                   const int* __restrict__ dst,
                                                   int* __restrict__ bcur,
                                                   int* __restrict__ ebuf, int E) {
    __shared__ int lh[512];
    __shared__ int gb[512];
    int t = threadIdx.x;
    lh[t] = 0;
    lh[t + 256] = 0;
    __syncthreads();
    int base = blockIdx.x * 4096;
    unsigned pk[16];  // rank<<17 | bkt<<8 | dlocal
#pragma unroll
    for (int i = 0; i < 16; ++i) {
        int e = base + i * 256 + t;
        unsigned p = 0xFFFFFFFFu;
        if (e < E) {
            int d = dst[e];
            int bkt = d >> 8;
            int r = atomicAdd(&lh[bkt], 1);
            p = ((unsigned)r << 17) | ((unsigned)bkt << 8) | (unsigned)(d & 255);
        }
        pk[i] = p;
    }
    __syncthreads();
    if (lh[t]) gb[t] = atomicAdd(&bcur[t], lh[t]);
    if (lh[t + 256]) gb[t + 256] = atomicAdd(&bcur[t + 256], lh[t + 256]);
    __syncthreads();
#pragma unroll
    for (int i = 0; i < 16; ++i) {
        int e = base + i * 256 + t;
        if (e < E) {
            unsigned p = pk[i];
            int bkt = (p >> 8) & 511;
            int r = (int)(p >> 17);
            ebuf[gb[bkt] + r] = src[e] | ((int)(p & 255) << 20);
        }
    }
}

__global__ __launch_bounds__(256) void bkt_build(const int* __restrict__ ebuf,
                                                 const int* __restrict__ boff,
                                                 int* __restrict__ row_ptr,
                                                 int* __restrict__ csr, int N) {
    __shared__ int lcnt[256];
    __shared__ int lofs[256];
    __shared__ int lcur[256];
    int t = threadIdx.x;
    int b = blockIdx.x;
    int base = b << 8;
    int ebeg = boff[b], eend = boff[b + 1];
    lcnt[t] = 0;
    __syncthreads();
    for (int e = ebeg + t; e < eend; e += 256)
        atomicAdd(&lcnt[((unsigned)ebuf[e]) >> 20], 1);
    __syncthreads();
    int v = lcnt[t];
    lofs[t] = v;
    __syncthreads();
    for (int off = 1; off < 256; off <<= 1) {
        int u = (t >= off) ? lofs[t - off] : 0;
        __syncthreads();
        lofs[t] += u;
        __syncthreads();
    }
    int ex = lofs[t] - v;
    __syncthreads();
    lofs[t] = ex;
    lcur[t] = 0;
    if (base + t < N) row_ptr[base + t] = ebeg + ex;
    __syncthreads();
    for (int e = ebeg + t; e < eend; e += 256) {
        int u = ebuf[e];
        int d = ((unsigned)u) >> 20;
        int r = atomicAdd(&lcur[d], 1);
        csr[ebeg + lofs[d] + r] = u & 0xFFFFF;
    }
}

// ================= fp32 -> bf16 casts =================

__global__ __launch_bounds__(256) void cast_x_kernel(const float* __restrict__ src,
                                                     ushort_t* __restrict__ dst,
                                                     long n) {
    long i = ((long)blockIdx.x * 256 + threadIdx.x) * 8;
    if (i >= n) return;
    float4 a = *(const float4*)(src + i);
    float4 b = *(const float4*)(src + i + 4);
    uint4 o;
    o.x = (uint_t)f2bf(a.x) | ((uint_t)f2bf(a.y) << 16);
    o.y = (uint_t)f2bf(a.z) | ((uint_t)f2bf(a.w) << 16);
    o.z = (uint_t)f2bf(b.x) | ((uint_t)f2bf(b.y) << 16);
    o.w = (uint_t)f2bf(b.z) | ((uint_t)f2bf(b.w) << 16);
    *(uint4*)(dst + i) = o;
}

__global__ __launch_bounds__(256) void cast_w_kernel(const float* __restrict__ s0,
                                                     const float* __restrict__ s1,
                                                     const float* __restrict__ s2,
                                                     const float* __restrict__ s3,
                                                     ushort_t* __restrict__ d0,
                                                     ushort_t* __restrict__ d1,
                                                     ushort_t* __restrict__ d2,
                                                     ushort_t* __restrict__ d3) {
    const float* s = (blockIdx.y == 0) ? s0 : (blockIdx.y == 1) ? s1
                   : (blockIdx.y == 2) ? s2 : s3;
    ushort_t* d = (blockIdx.y == 0) ? d0 : (blockIdx.y == 1) ? d1
                : (blockIdx.y == 2) ? d2 : d3;
    long i = ((long)blockIdx.x * 256 + threadIdx.x) * 8;
    float4 a = *(const float4*)(s + i);
    float4 b = *(const float4*)(s + i + 4);
    uint4 o;
    o.x = (uint_t)f2bf(a.x) | ((uint_t)f2bf(a.y) << 16);
    o.y = (uint_t)f2bf(a.z) | ((uint_t)f2bf(a.w) << 16);
    o.z = (uint_t)f2bf(b.x) | ((uint_t)f2bf(b.y) << 16);
    o.w = (uint_t)f2bf(b.z) | ((uint_t)f2bf(b.w) << 16);
    *(uint4*)(d + i) = o;
}

// ================= mean aggregation over bf16 rows =================
// One wave per node. 32 lanes x uint2 (8B) per row; the two wave-halves gather
// TWO different neighbor rows per load instruction (512 B/inst, 16 rows in
// flight in the main loop). Halves combined at the end via shfl_xor(32).

__global__ __launch_bounds__(256) void agg_b_kernel(const ushort_t* __restrict__ xin,
                                                    const int* __restrict__ csr,
                                                    const int* __restrict__ row_ptr,
                                                    ushort_t* __restrict__ aggb, int N) {
    int node = blockIdx.x * 4 + (threadIdx.x >> 6);
    if (node >= N) return;
    int lane = threadIdx.x & 63;
    int half = lane >> 5;   // which neighbor of the pair
    int l32 = lane & 31;    // elems 4*l32 .. 4*l32+3
    int beg = row_ptr[node], end = row_ptr[node + 1];
    int deg = end - beg;
    float a0 = 0.f, a1 = 0.f, a2 = 0.f, a3 = 0.f;
    int e = beg;
    // 16-neighbor batches: 8 paired loads in flight
    for (; e + 16 <= end; e += 16) {
        uint2 v[8];
#pragma unroll
        for (int q = 0; q < 8; ++q) {
            int s = csr[e + 2 * q + half];
            v[q] = ((const uint2*)(xin + (size_t)s * D))[l32];
        }
#pragma unroll
        for (int q = 0; q < 8; ++q) {
            a0 += bf_lo(v[q].x); a1 += bf_hi(v[q].x);
            a2 += bf_lo(v[q].y); a3 += bf_hi(v[q].y);
        }
    }
    // 8-neighbor batch
    if (e + 8 <= end) {
        uint2 v[4];
#pragma unroll
        for (int q = 0; q < 4; ++q) {
            int s = csr[e + 2 * q + half];
            v[q] = ((const uint2*)(xin + (size_t)s * D))[l32];
        }
#pragma unroll
        for (int q = 0; q < 4; ++q) {
            a0 += bf_lo(v[q].x); a1 += bf_hi(v[q].x);
            a2 += bf_lo(v[q].y); a3 += bf_hi(v[q].y);
        }
        e += 8;
    }
    // 4-neighbor batch
    if (e + 4 <= end) {
        uint2 v[2];
#pragma unroll
        for (int q = 0; q < 2; ++q) {
            int s = csr[e + 2 * q + half];
            v[q] = ((const uint2*)(xin + (size_t)s * D))[l32];
        }
#pragma unroll
        for (int q = 0; q < 2; ++q) {
            a0 += bf_lo(v[q].x); a1 += bf_hi(v[q].x);
            a2 += bf_lo(v[q].y); a3 += bf_hi(v[q].y);
        }
        e += 4;
    }
    // pair
    if (e + 2 <= end) {
        int s = csr[e + half];
        uint2 v = ((const uint2*)(xin + (size_t)s * D))[l32];
        a0 += bf_lo(v.x); a1 += bf_hi(v.x);
        a2 += bf_lo(v.y); a3 += bf_hi(v.y);
        e += 2;
    }
    // odd last neighbor: only half 0
    if (e < end && half == 0) {
        int s = csr[e];
        uint2 v = ((const uint2*)(xin + (size_t)s * D))[l32];
        a0 += bf_lo(v.x); a1 += bf_hi(v.x);
        a2 += bf_lo(v.y); a3 += bf_hi(v.y);
    }
    // combine the two halves
    a0 += __shfl_xor(a0, 32, 64);
    a1 += __shfl_xor(a1, 32, 64);
    a2 += __shfl_xor(a2, 32, 64);
    a3 += __shfl_xor(a3, 32, 64);
    if (half == 0) {
        float inv = 1.0f / fmaxf((float)deg, 1.0f);
        uint2 o;
        o.x = (uint_t)f2bf(a0 * inv) | ((uint_t)f2bf(a1 * inv) << 16);
        o.y = (uint_t)f2bf(a2 * inv) | ((uint_t)f2bf(a3 * inv) << 16);
        ((uint2*)(aggb + (size_t)node * D))[l32] = o;
    }
}

// ================= MFMA GEMM: out = [aggb|xinb] @ [Wl|Wr]^T + bias =================

__global__ __launch_bounds__(256) void gemm_mfma(const ushort_t* __restrict__ Aagg,
                                                 const ushort_t* __restrict__ Ax,
                                                 const ushort_t* __restrict__ Wl,
                                                 const ushort_t* __restrict__ Wr,
                                                 const float* __restrict__ bias,
                                                 ushort_t* __restrict__ out_bf,
                                                 float* __restrict__ out_f32,
                                                 int N, int relu_bf) {
    int tid = threadIdx.x;
    int wave = tid >> 6, lane = tid & 63;
    int quad = lane >> 4, l15 = lane & 15;
    int mg = wave & 1, cg = wave >> 1;
    int n0 = blockIdx.x * 64;

    f32x4 acc[2][4];
#pragma unroll
    for (int mt = 0; mt < 2; ++mt)
#pragma unroll
        for (int nt = 0; nt < 4; ++nt) acc[mt][nt] = (f32x4){0.f, 0.f, 0.f, 0.f};

    int r0 = min(n0 + mg * 32 + l15, N - 1);
    int r1 = min(n0 + mg * 32 + 16 + l15, N - 1);
    int jb = cg * 64 + l15;

#pragma unroll
    for (int c = 0; c < 8; ++c) {
        const ushort_t* Ab = (c < 4) ? Aagg : Ax;
        const ushort_t* Wb = (c < 4) ? Wl : Wr;
        int koff = (c & 3) * 32 + quad * 8;
        bf16x8 a0 = *(const bf16x8*)(Ab + (size_t)r0 * D + koff);
        bf16x8 a1 = *(const bf16x8*)(Ab + (size_t)r1 * D + koff);
        bf16x8 b0 = *(const bf16x8*)(Wb + (size_t)(jb + 0) * D + koff);
        bf16x8 b1 = *(const bf16x8*)(Wb + (size_t)(jb + 16) * D + koff);
        bf16x8 b2 = *(const bf16x8*)(Wb + (size_t)(jb + 32) * D + koff);
        bf16x8 b3 = *(const bf16x8*)(Wb + (size_t)(jb + 48) * D + koff);
        acc[0][0] = __builtin_amdgcn_mfma_f32_16x16x32_bf16(a0, b0, acc[0][0], 0, 0, 0);
        acc[0][1] = __builtin_amdgcn_mfma_f32_16x16x32_bf16(a0, b1, acc[0][1], 0, 0, 0);
        acc[0][2] = __builtin_amdgcn_mfma_f32_16x16x32_bf16(a0, b2, acc[0][2], 0, 0, 0);
        acc[0][3] = __builtin_amdgcn_mfma_f32_16x16x32_bf16(a0, b3, acc[0][3], 0, 0, 0);
        acc[1][0] = __builtin_amdgcn_mfma_f32_16x16x32_bf16(a1, b0, acc[1][0], 0, 0, 0);
        acc[1][1] = __builtin_amdgcn_mfma_f32_16x16x32_bf16(a1, b1, acc[1][1], 0, 0, 0);
        acc[1][2] = __builtin_amdgcn_mfma_f32_16x16x32_bf16(a1, b2, acc[1][2], 0, 0, 0);
        acc[1][3] = __builtin_amdgcn_mfma_f32_16x16x32_bf16(a1, b3, acc[1][3], 0, 0, 0);
    }

#pragma unroll
    for (int mt = 0; mt < 2; ++mt) {
#pragma unroll
        for (int nt = 0; nt < 4; ++nt) {
            int col = cg * 64 + nt * 16 + l15;
            float bv = bias[col];
#pragma unroll
            for (int reg = 0; reg < 4; ++reg) {
                int row = n0 + mg * 32 + mt * 16 + quad * 4 + reg;
                if (row < N) {
                    float v = acc[mt][nt][reg] + bv;
                    if (relu_bf) {
                        v = fmaxf(v, 0.f);
                        out_bf[(size_t)row * D + col] = f2bf(v);
                    } else {
                        out_f32[(size_t)row * D + col] = v;
                    }
                }
            }
        }
    }
}

// ================= launch =================

extern "C" void kernel_launch(void* const* d_in, const int* in_sizes, int n_in,
                              void* d_out, int out_size, void* d_ws, size_t ws_size,
                              hipStream_t stream) {
    const float* x   = (const float*)d_in[0];
    const int*   ei  = (const int*)d_in[1];
    const float* W1l = (const float*)d_in[2];
    const float* b1  = (const float*)d_in[3];
    const float* W1r = (const float*)d_in[4];
    const float* W2l = (const float*)d_in[5];
    const float* b2  = (const float*)d_in[6];
    const float* W2r = (const float*)d_in[7];
    float* out = (float*)d_out;

    int N = in_sizes[0] / D;
    int E = in_sizes[1] / 2;
    const int* src = ei;
    const int* dst = ei + E;

    char* ws = (char*)d_ws;
    size_t off = 0;
    auto take = [&](size_t bytes) -> char* {
        char* p = ws + off;
        off += (bytes + 255) & ~(size_t)255;
        return p;
    };
    int*      row_ptr = (int*)take((size_t)(N + 1) * sizeof(int));
    int*      bhist   = (int*)take((size_t)(512 + 512 + 513) * sizeof(int));
    int*      bcur    = bhist + 512;
    int*      boff    = bhist + 1024;
    int*      ebuf    = (int*)take((size_t)E * sizeof(int));
    int*      csr     = (int*)take((size_t)E * sizeof(int));
    ushort_t* xb      = (ushort_t*)take((size_t)N * D * sizeof(ushort_t));
    ushort_t* hb      = (ushort_t*)take((size_t)N * D * sizeof(ushort_t));
    ushort_t* aggb    = (ushort_t*)take((size_t)N * D * sizeof(ushort_t));
    ushort_t* W1lb    = (ushort_t*)take((size_t)D * D * sizeof(ushort_t));
    ushort_t* W1rb    = (ushort_t*)take((size_t)D * D * sizeof(ushort_t));
    ushort_t* W2lb    = (ushort_t*)take((size_t)D * D * sizeof(ushort_t));
    ushort_t* W2rb    = (ushort_t*)take((size_t)D * D * sizeof(ushort_t));
    (void)ws_size;
    (void)n_in;
    (void)out_size;

    hipMemsetAsync(bhist, 0, 1024 * sizeof(int), stream);

    int NB = (N + 255) / 256;
    int EB = (E + 4095) / 4096;

    bkt_hist<<<EB, 256, 0, stream>>>(dst, bhist, E);
    bkt_scan<<<1, 512, 0, stream>>>(bhist, boff, bcur, row_ptr, N, E);
    bkt_scatter<<<EB, 256, 0, stream>>>(src, dst, bcur, ebuf, E);
    bkt_build<<<NB, 256, 0, stream>>>(ebuf, boff, row_ptr, csr, N);

    long nx = (long)N * D;
    cast_x_kernel<<<(int)((nx / 8 + 255) / 256), 256, 0, stream>>>(x, xb, nx);
    cast_w_kernel<<<dim3(8, 4), 256, 0, stream>>>(W1l, W1r, W2l, W2r,
                                                  W1lb, W1rb, W2lb, W2rb);

    int ablocks = (N + 3) / 4;
    int gblocks = (N + 63) / 64;

    agg_b_kernel<<<ablocks, 256, 0, stream>>>(xb, csr, row_ptr, aggb, N);
    gemm_mfma<<<gblocks, 256, 0, stream>>>(aggb, xb, W1lb, W1rb, b1, hb, nullptr, N, 1);

    agg_b_kernel<<<ablocks, 256, 0, stream>>>(hb, csr, row_ptr, aggb, N);
    gemm_mfma<<<gblocks, 256, 0, stream>>>(aggb, hb, W2lb, W2rb, b2, nullptr, out, N, 0);
}

// Round 7
// 347.908 us; speedup vs baseline: 2.6371x; 1.1006x over previous
//
#include <hip/hip_runtime.h>
#include <cstdint>
#include <cstddef>

#define D 128

typedef unsigned short ushort_t;
typedef unsigned int uint_t;
typedef __attribute__((ext_vector_type(8))) short bf16x8;
typedef __attribute__((ext_vector_type(4))) float f32x4;

static __device__ __forceinline__ unsigned short f2bf(float f) {
    unsigned int u = __float_as_uint(f);
    u = (u + 0x7FFFu + ((u >> 16) & 1u)) >> 16;  // RNE
    return (unsigned short)u;
}
static __device__ __forceinline__ float bf_lo(uint_t v) {
    return __uint_as_float(v << 16);
}
static __device__ __forceinline__ float bf_hi(uint_t v) {
    return __uint_as_float(v & 0xFFFF0000u);
}

// ================= CSR build: two-level counting sort =================

__global__ __launch_bounds__(256) void bkt_hist(const int* __restrict__ dst,
                                                int* __restrict__ bhist, int E) {
    __shared__ int lh[512];
    int t = threadIdx.x;
    lh[t] = 0;
    lh[t + 256] = 0;
    __syncthreads();
    int base = blockIdx.x * 4096;
#pragma unroll
    for (int i = 0; i < 16; ++i) {
        int e = base + i * 256 + t;
        if (e < E) atomicAdd(&lh[dst[e] >> 8], 1);
    }
    __syncthreads();
    if (lh[t]) atomicAdd(&bhist[t], lh[t]);
    if (lh[t + 256]) atomicAdd(&bhist[t + 256], lh[t + 256]);
}

__global__ __launch_bounds__(512) void bkt_scan(const int* __restrict__ bhist,
                                                int* __restrict__ boff,
                                                int* __restrict__ bcur,
                                                int* __restrict__ row_ptr,
                                                int N, int E) {
    __shared__ int s[512];
    int t = threadIdx.x;
    int v = bhist[t];
    s[t] = v;
    __syncthreads();
    for (int off = 1; off < 512; off <<= 1) {
        int u = (t >= off) ? s[t - off] : 0;
        __syncthreads();
        s[t] += u;
        __syncthreads();
    }
    int ex = s[t] - v;
    boff[t] = ex;
    bcur[t] = ex;
    if (t == 511) boff[512] = s[511];
    if (t == 0) row_ptr[N] = E;
}

__global__ __launch_bounds__(256) void bkt_scatter(const int* __restrict__ src,
                                                   const int* __restrict__ dst,
                                                   int* __restrict__ bcur,
                                                   int* __restrict__ ebuf, int E) {
    __shared__ int lh[512];
    __shared__ int gb[512];
    int t = threadIdx.x;
    lh[t] = 0;
    lh[t + 256] = 0;
    __syncthreads();
    int base = blockIdx.x * 4096;
    unsigned pk[16];  // rank<<17 | bkt<<8 | dlocal
#pragma unroll
    for (int i = 0; i < 16; ++i) {
        int e = base + i * 256 + t;
        unsigned p = 0xFFFFFFFFu;
        if (e < E) {
            int d = dst[e];
            int bkt = d >> 8;
            int r = atomicAdd(&lh[bkt], 1);
            p = ((unsigned)r << 17) | ((unsigned)bkt << 8) | (unsigned)(d & 255);
        }
        pk[i] = p;
    }
    __syncthreads();
    if (lh[t]) gb[t] = atomicAdd(&bcur[t], lh[t]);
    if (lh[t + 256]) gb[t + 256] = atomicAdd(&bcur[t + 256], lh[t + 256]);
    __syncthreads();
#pragma unroll
    for (int i = 0; i < 16; ++i) {
        int e = base + i * 256 + t;
        if (e < E) {
            unsigned p = pk[i];
            int bkt = (p >> 8) & 511;
            int r = (int)(p >> 17);
            ebuf[gb[bkt] + r] = src[e] | ((int)(p & 255) << 20);
        }
    }
}

__global__ __launch_bounds__(256) void bkt_build(const int* __restrict__ ebuf,
                                                 const int* __restrict__ boff,
                                                 int* __restrict__ row_ptr,
                                                 int* __restrict__ csr, int N) {
    __shared__ int lcnt[256];
    __shared__ int lofs[256];
    __shared__ int lcur[256];
    int t = threadIdx.x;
    int b = blockIdx.x;
    int base = b << 8;
    int ebeg = boff[b], eend = boff[b + 1];
    lcnt[t] = 0;
    __syncthreads();
    for (int e = ebeg + t; e < eend; e += 256)
        atomicAdd(&lcnt[((unsigned)ebuf[e]) >> 20], 1);
    __syncthreads();
    int v = lcnt[t];
    lofs[t] = v;
    __syncthreads();
    for (int off = 1; off < 256; off <<= 1) {
        int u = (t >= off) ? lofs[t - off] : 0;
        __syncthreads();
        lofs[t] += u;
        __syncthreads();
    }
    int ex = lofs[t] - v;
    __syncthreads();
    lofs[t] = ex;
    lcur[t] = 0;
    if (base + t < N) row_ptr[base + t] = ebeg + ex;
    __syncthreads();
    for (int e = ebeg + t; e < eend; e += 256) {
        int u = ebuf[e];
        int d = ((unsigned)u) >> 20;
        int r = atomicAdd(&lcur[d], 1);
        csr[ebeg + lofs[d] + r] = u & 0xFFFFF;
    }
}

// ================= fp32 -> bf16 casts =================

__global__ __launch_bounds__(256) void cast_x_kernel(const float* __restrict__ src,
                                                     ushort_t* __restrict__ dst,
                                                     long n) {
    long i = ((long)blockIdx.x * 256 + threadIdx.x) * 8;
    if (i >= n) return;
    float4 a = *(const float4*)(src + i);
    float4 b = *(const float4*)(src + i + 4);
    uint4 o;
    o.x = (uint_t)f2bf(a.x) | ((uint_t)f2bf(a.y) << 16);
    o.y = (uint_t)f2bf(a.z) | ((uint_t)f2bf(a.w) << 16);
    o.z = (uint_t)f2bf(b.x) | ((uint_t)f2bf(b.y) << 16);
    o.w = (uint_t)f2bf(b.z) | ((uint_t)f2bf(b.w) << 16);
    *(uint4*)(dst + i) = o;
}

__global__ __launch_bounds__(256) void cast_w_kernel(const float* __restrict__ s0,
                                                     const float* __restrict__ s1,
                                                     const float* __restrict__ s2,
                                                     const float* __restrict__ s3,
                                                     ushort_t* __restrict__ d0,
                                                     ushort_t* __restrict__ d1,
                                                     ushort_t* __restrict__ d2,
                                                     ushort_t* __restrict__ d3) {
    const float* s = (blockIdx.y == 0) ? s0 : (blockIdx.y == 1) ? s1
                   : (blockIdx.y == 2) ? s2 : s3;
    ushort_t* d = (blockIdx.y == 0) ? d0 : (blockIdx.y == 1) ? d1
                : (blockIdx.y == 2) ? d2 : d3;
    long i = ((long)blockIdx.x * 256 + threadIdx.x) * 8;
    float4 a = *(const float4*)(s + i);
    float4 b = *(const float4*)(s + i + 4);
    uint4 o;
    o.x = (uint_t)f2bf(a.x) | ((uint_t)f2bf(a.y) << 16);
    o.y = (uint_t)f2bf(a.z) | ((uint_t)f2bf(a.w) << 16);
    o.z = (uint_t)f2bf(b.x) | ((uint_t)f2bf(b.y) << 16);
    o.w = (uint_t)f2bf(b.z) | ((uint_t)f2bf(b.w) << 16);
    *(uint4*)(d + i) = o;
}

// ================= mean aggregation over bf16 rows =================
// One wave per node, paired-row uint2 gathers (scattered-line L2 service bound).

__global__ __launch_bounds__(256) void agg_b_kernel(const ushort_t* __restrict__ xin,
                                                    const int* __restrict__ csr,
                                                    const int* __restrict__ row_ptr,
                                                    ushort_t* __restrict__ aggb, int N) {
    int node = blockIdx.x * 4 + (threadIdx.x >> 6);
    if (node >= N) return;
    int lane = threadIdx.x & 63;
    int half = lane >> 5;
    int l32 = lane & 31;
    int beg = row_ptr[node], end = row_ptr[node + 1];
    int deg = end - beg;
    float a0 = 0.f, a1 = 0.f, a2 = 0.f, a3 = 0.f;
    int e = beg;
    for (; e + 16 <= end; e += 16) {
        uint2 v[8];
#pragma unroll
        for (int q = 0; q < 8; ++q) {
            int s = csr[e + 2 * q + half];
            v[q] = ((const uint2*)(xin + (size_t)s * D))[l32];
        }
#pragma unroll
        for (int q = 0; q < 8; ++q) {
            a0 += bf_lo(v[q].x); a1 += bf_hi(v[q].x);
            a2 += bf_lo(v[q].y); a3 += bf_hi(v[q].y);
        }
    }
    if (e + 8 <= end) {
        uint2 v[4];
#pragma unroll
        for (int q = 0; q < 4; ++q) {
            int s = csr[e + 2 * q + half];
            v[q] = ((const uint2*)(xin + (size_t)s * D))[l32];
        }
#pragma unroll
        for (int q = 0; q < 4; ++q) {
            a0 += bf_lo(v[q].x); a1 += bf_hi(v[q].x);
            a2 += bf_lo(v[q].y); a3 += bf_hi(v[q].y);
        }
        e += 8;
    }
    if (e + 4 <= end) {
        uint2 v[2];
#pragma unroll
        for (int q = 0; q < 2; ++q) {
            int s = csr[e + 2 * q + half];
            v[q] = ((const uint2*)(xin + (size_t)s * D))[l32];
        }
#pragma unroll
        for (int q = 0; q < 2; ++q) {
            a0 += bf_lo(v[q].x); a1 += bf_hi(v[q].x);
            a2 += bf_lo(v[q].y); a3 += bf_hi(v[q].y);
        }
        e += 4;
    }
    if (e + 2 <= end) {
        int s = csr[e + half];
        uint2 v = ((const uint2*)(xin + (size_t)s * D))[l32];
        a0 += bf_lo(v.x); a1 += bf_hi(v.x);
        a2 += bf_lo(v.y); a3 += bf_hi(v.y);
        e += 2;
    }
    if (e < end && half == 0) {
        int s = csr[e];
        uint2 v = ((const uint2*)(xin + (size_t)s * D))[l32];
        a0 += bf_lo(v.x); a1 += bf_hi(v.x);
        a2 += bf_lo(v.y); a3 += bf_hi(v.y);
    }
    a0 += __shfl_xor(a0, 32, 64);
    a1 += __shfl_xor(a1, 32, 64);
    a2 += __shfl_xor(a2, 32, 64);
    a3 += __shfl_xor(a3, 32, 64);
    if (half == 0) {
        float inv = 1.0f / fmaxf((float)deg, 1.0f);
        uint2 o;
        o.x = (uint_t)f2bf(a0 * inv) | ((uint_t)f2bf(a1 * inv) << 16);
        o.y = (uint_t)f2bf(a2 * inv) | ((uint_t)f2bf(a3 * inv) << 16);
        ((uint2*)(aggb + (size_t)node * D))[l32] = o;
    }
}

// ================= MFMA GEMM (LDS-staged): out = [aggb|xinb] @ [Wl|Wr]^T + bias ====
// Block: 256 thr = 4 waves; tile 128 nodes x 128 cols. Wave (wm,wc) owns 64x64.
// Per K-chunk of 32: stage sA(8KB)+sW(8KB) with fully-coalesced global loads,
// fragments via ds_read_b128 (k-contiguous rows), 16 MFMA/wave/chunk.
// A-frag: lane=row m (l15), k=quad*8+j.  B-frag: lane=col j, same k slice.
// C/D: col=lane&15, row=quad*4+reg.

__global__ __launch_bounds__(256) void gemm_mfma(const ushort_t* __restrict__ Aagg,
                                                 const ushort_t* __restrict__ Ax,
                                                 const ushort_t* __restrict__ Wl,
                                                 const ushort_t* __restrict__ Wr,
                                                 const float* __restrict__ bias,
                                                 ushort_t* __restrict__ out_bf,
                                                 float* __restrict__ out_f32,
                                                 int N, int relu_bf) {
    __shared__ ushort_t sA[128 * 32];  // 8 KB, row-major, row stride 32 elems
    __shared__ ushort_t sW[128 * 32];  // 8 KB
    int tid = threadIdx.x;
    int wave = tid >> 6, lane = tid & 63;
    int quad = lane >> 4, l15 = lane & 15;
    int wm = wave & 1, wc = wave >> 1;
    int n0 = blockIdx.x * 128;

    // staging coords: each thread moves 2x16B for A and 2x16B for W per chunk
    int sr = tid >> 2;          // rows 0..63 (iter adds 64)
    int sseg = (tid & 3) * 8;   // elem offset within 32-elem row

    f32x4 acc[4][4];
#pragma unroll
    for (int mt = 0; mt < 4; ++mt)
#pragma unroll
        for (int nt = 0; nt < 4; ++nt) acc[mt][nt] = (f32x4){0.f, 0.f, 0.f, 0.f};

    int ga0 = min(n0 + sr, N - 1);
    int ga1 = min(n0 + sr + 64, N - 1);

#pragma unroll
    for (int c = 0; c < 8; ++c) {
        const ushort_t* Ab = (c < 4) ? Aagg : Ax;
        const ushort_t* Wb = (c < 4) ? Wl : Wr;
        int koff = (c & 3) * 32 + sseg;
        bf16x8 va0 = *(const bf16x8*)(Ab + (size_t)ga0 * D + koff);
        bf16x8 va1 = *(const bf16x8*)(Ab + (size_t)ga1 * D + koff);
        bf16x8 vw0 = *(const bf16x8*)(Wb + (size_t)sr * D + koff);
        bf16x8 vw1 = *(const bf16x8*)(Wb + (size_t)(sr + 64) * D + koff);
        __syncthreads();  // previous chunk fully consumed
        *(bf16x8*)&sA[sr * 32 + sseg] = va0;
        *(bf16x8*)&sA[(sr + 64) * 32 + sseg] = va1;
        *(bf16x8*)&sW[sr * 32 + sseg] = vw0;
        *(bf16x8*)&sW[(sr + 64) * 32 + sseg] = vw1;
        __syncthreads();

        bf16x8 af[4], wf[4];
#pragma unroll
        for (int mt = 0; mt < 4; ++mt)
            af[mt] = *(const bf16x8*)&sA[(wm * 64 + mt * 16 + l15) * 32 + quad * 8];
#pragma unroll
        for (int nt = 0; nt < 4; ++nt)
            wf[nt] = *(const bf16x8*)&sW[(wc * 64 + nt * 16 + l15) * 32 + quad * 8];
#pragma unroll
        for (int mt = 0; mt < 4; ++mt)
#pragma unroll
            for (int nt = 0; nt < 4; ++nt)
                acc[mt][nt] = __builtin_amdgcn_mfma_f32_16x16x32_bf16(
                    af[mt], wf[nt], acc[mt][nt], 0, 0, 0);
    }

#pragma unroll
    for (int mt = 0; mt < 4; ++mt) {
#pragma unroll
        for (int nt = 0; nt < 4; ++nt) {
            int col = wc * 64 + nt * 16 + l15;
            float bv = bias[col];
#pragma unroll
            for (int reg = 0; reg < 4; ++reg) {
                int row = n0 + wm * 64 + mt * 16 + quad * 4 + reg;
                if (row < N) {
                    float v = acc[mt][nt][reg] + bv;
                    if (relu_bf) {
                        v = fmaxf(v, 0.f);
                        out_bf[(size_t)row * D + col] = f2bf(v);
                    } else {
                        out_f32[(size_t)row * D + col] = v;
                    }
                }
            }
        }
    }
}

// ================= launch =================

extern "C" void kernel_launch(void* const* d_in, const int* in_sizes, int n_in,
                              void* d_out, int out_size, void* d_ws, size_t ws_size,
                              hipStream_t stream) {
    const float* x   = (const float*)d_in[0];
    const int*   ei  = (const int*)d_in[1];
    const float* W1l = (const float*)d_in[2];
    const float* b1  = (const float*)d_in[3];
    const float* W1r = (const float*)d_in[4];
    const float* W2l = (const float*)d_in[5];
    const float* b2  = (const float*)d_in[6];
    const float* W2r = (const float*)d_in[7];
    float* out = (float*)d_out;

    int N = in_sizes[0] / D;
    int E = in_sizes[1] / 2;
    const int* src = ei;
    const int* dst = ei + E;

    char* ws = (char*)d_ws;
    size_t off = 0;
    auto take = [&](size_t bytes) -> char* {
        char* p = ws + off;
        off += (bytes + 255) & ~(size_t)255;
        return p;
    };
    int*      row_ptr = (int*)take((size_t)(N + 1) * sizeof(int));
    int*      bhist   = (int*)take((size_t)(512 + 512 + 513) * sizeof(int));
    int*      bcur    = bhist + 512;
    int*      boff    = bhist + 1024;
    int*      ebuf    = (int*)take((size_t)E * sizeof(int));
    int*      csr     = (int*)take((size_t)E * sizeof(int));
    ushort_t* xb      = (ushort_t*)take((size_t)N * D * sizeof(ushort_t));
    ushort_t* hb      = (ushort_t*)take((size_t)N * D * sizeof(ushort_t));
    ushort_t* aggb    = (ushort_t*)take((size_t)N * D * sizeof(ushort_t));
    ushort_t* W1lb    = (ushort_t*)take((size_t)D * D * sizeof(ushort_t));
    ushort_t* W1rb    = (ushort_t*)take((size_t)D * D * sizeof(ushort_t));
    ushort_t* W2lb    = (ushort_t*)take((size_t)D * D * sizeof(ushort_t));
    ushort_t* W2rb    = (ushort_t*)take((size_t)D * D * sizeof(ushort_t));
    (void)ws_size;
    (void)n_in;
    (void)out_size;

    hipMemsetAsync(bhist, 0, 1024 * sizeof(int), stream);

    int NB = (N + 255) / 256;
    int EB = (E + 4095) / 4096;

    bkt_hist<<<EB, 256, 0, stream>>>(dst, bhist, E);
    bkt_scan<<<1, 512, 0, stream>>>(bhist, boff, bcur, row_ptr, N, E);
    bkt_scatter<<<EB, 256, 0, stream>>>(src, dst, bcur, ebuf, E);
    bkt_build<<<NB, 256, 0, stream>>>(ebuf, boff, row_ptr, csr, N);

    long nx = (long)N * D;
    cast_x_kernel<<<(int)((nx / 8 + 255) / 256), 256, 0, stream>>>(x, xb, nx);
    cast_w_kernel<<<dim3(8, 4), 256, 0, stream>>>(W1l, W1r, W2l, W2r,
                                                  W1lb, W1rb, W2lb, W2rb);

    int ablocks = (N + 3) / 4;
    int gblocks = (N + 127) / 128;

    agg_b_kernel<<<ablocks, 256, 0, stream>>>(xb, csr, row_ptr, aggb, N);
    gemm_mfma<<<gblocks, 256, 0, stream>>>(aggb, xb, W1lb, W1rb, b1, hb, nullptr, N, 1);

    agg_b_kernel<<<ablocks, 256, 0, stream>>>(hb, csr, row_ptr, aggb, N);
    gemm_mfma<<<gblocks, 256, 0, stream>>>(aggb, hb, W2lb, W2rb, b2, nullptr, out, N, 0);
}